// Round 13
// baseline (89.766 us; speedup 1.0000x reference)
//
#include <hip/hip_runtime.h>
#include <hip/hip_bf16.h>

#define NH 4
#define HD 64
#define HID 256
#define SS 4096

#define QFRAG_PER_HEAD (128 * 6 * 64 * 8)   // 393216 elems
#define KFRAG_PER_HEAD (64 * 12 * 64 * 8)   // 393216 elems
#define VFRAG_PER_HEAD (64 * 8 * 64 * 8)    // 262144 elems

typedef float f4 __attribute__((ext_vector_type(4)));
typedef float f16v __attribute__((ext_vector_type(16)));
typedef short bf8 __attribute__((ext_vector_type(8)));   // 8 bf16
typedef unsigned int u4v __attribute__((ext_vector_type(4)));

static __device__ __forceinline__ float fast_exp2(float x) {
#if __has_builtin(__builtin_amdgcn_exp2f)
    return __builtin_amdgcn_exp2f(x);
#else
    float r; asm("v_exp_f32 %0, %1" : "=v"(r) : "v"(x)); return r;
#endif
}

static __device__ __forceinline__ unsigned pack2(float a, float b) {
    unsigned ua = (unsigned)__bfloat16_as_ushort(__float2bfloat16(a));
    unsigned ub = (unsigned)__bfloat16_as_ushort(__float2bfloat16(b));
    return ua | (ub << 16);
}

// single-instruction packed f32x2 -> bf16x2 (T12; no builtin on gfx950)
static __device__ __forceinline__ unsigned cvtpk(float a, float b) {
    unsigned r;
    asm("v_cvt_pk_bf16_f32 %0, %1, %2" : "=v"(r) : "v"(a), "v"(b));
    return r;
}

// ---------------------------------------------------------------------------
// Setup: codon->group-id map + beta*log2e.
// ---------------------------------------------------------------------------
__global__ void setup_kernel(const float* __restrict__ syn,
                             int* __restrict__ gid, float* __restrict__ betaP)
{
    const int lane = threadIdx.x;          // 0..63
    int rep = 64;
    for (int j = 63; j >= 0; --j)
        if (syn[lane * 64 + j] != 0.0f) rep = j;
    if (rep == 64) rep = lane;
    unsigned long long m = __ballot(rep == lane);
    int id = (int)__popcll(m & ((2ull << rep) - 1ull)) - 1;
    if (id < 0) id = 0;
    gid[lane] = id;                                 // 0..20
    if (lane == 0) *betaP = syn[0] * 1.44269504088896f;
}

// ---------------------------------------------------------------------------
// Pack wq/wk/wv/wo into MFMA fragment-major bf16.
// ---------------------------------------------------------------------------
__global__ __launch_bounds__(256)
void pack_w_kernel(const float* __restrict__ wq, const float* __restrict__ wk,
                   const float* __restrict__ wv, const float* __restrict__ wo,
                   __hip_bfloat16* __restrict__ wpk)
{
    const int t = blockIdx.x * 256 + threadIdx.x;   // 0..32767
    const int mat = t >> 13;
    const int r = t & 8191;
    const int dt = r >> 10, ks = (r >> 6) & 15, lane = r & 63;
    const float* w = (mat == 0) ? wq : (mat == 1) ? wk : (mat == 2) ? wv : wo;
    const int row = dt * 32 + (lane & 31);
    const int col = ks * 16 + (lane >> 5) * 8;
    const f4 a = *(const f4*)&w[(size_t)row * 256 + col];
    const f4 b = *(const f4*)&w[(size_t)row * 256 + col + 4];
    union { unsigned u[4]; bf8 v; } o;
    o.u[0] = pack2(a[0], a[1]); o.u[1] = pack2(a[2], a[3]);
    o.u[2] = pack2(b[0], b[1]); o.u[3] = pack2(b[2], b[3]);
    *(bf8*)&wpk[(size_t)t * 8] = o.v;
}

// ---------------------------------------------------------------------------
// QKV projection via MFMA (unchanged from R6).
// ---------------------------------------------------------------------------
__global__ __launch_bounds__(256)
void qkv_mfma_kernel(const float* __restrict__ x,
                     const __hip_bfloat16* __restrict__ wpk,
                     const float* __restrict__ bq, const float* __restrict__ bk,
                     const float* __restrict__ bv,
                     const int* __restrict__ codons,
                     const int* __restrict__ gid, const float* __restrict__ betaP,
                     __hip_bfloat16* __restrict__ qfrag,
                     __hip_bfloat16* __restrict__ kfrag,
                     __hip_bfloat16* __restrict__ vfrag)
{
    const int bid = blockIdx.x;
    const int stile = bid / 6;            // 0..255
    const int grp = bid % 6;
    const int tid = threadIdx.x;
    const int w = tid >> 6, lane = tid & 63, hi = lane >> 5, l5 = lane & 31;

    const int bidx = stile >> 7;
    const int stl = stile & 127;
    const int hs = stl & 1, tkv = stl >> 1;

    __shared__ __hip_bfloat16 xs[32][256];

    {
        const int r0 = tid >> 5, c = tid & 31;
        #pragma unroll
        for (int it = 0; it < 4; ++it) {
            const int row = r0 + it * 8;
            const f4 a = *(const f4*)&x[(size_t)(stile * 32 + row) * HID + c * 8];
            const f4 b2 = *(const f4*)&x[(size_t)(stile * 32 + row) * HID + c * 8 + 4];
            union { unsigned u[4]; bf8 v; } o;
            o.u[0] = pack2(a[0], a[1]); o.u[1] = pack2(a[2], a[3]);
            o.u[2] = pack2(b2[0], b2[1]); o.u[3] = pack2(b2[2], b2[3]);
            *(bf8*)&xs[row][((c ^ row) & 31) * 8] = o.v;
        }
    }
    __syncthreads();

    const int t24 = grp * 4 + w;          // 0..23
    const int mat = t24 >> 3;             // 0=q 1=k 2=v
    const int dt = t24 & 7;
    const int head = dt >> 1, d32 = dt & 1;

    const __hip_bfloat16* wb = wpk + (size_t)((mat * 8 + dt) * 16) * 512 + (size_t)lane * 8;
    bf8 wf[16];
    #pragma unroll
    for (int ks = 0; ks < 16; ++ks) wf[ks] = *(const bf8*)&wb[ks * 512];

    f16v acc;
    #pragma unroll
    for (int r = 0; r < 16; ++r) acc[r] = 0.0f;

    if (mat < 2) {
        #pragma unroll
        for (int ks = 0; ks < 16; ++ks) {
            const bf8 xf = *(const bf8*)&xs[l5][(((ks * 2 + hi) ^ l5) & 31) * 8];
            acc = __builtin_amdgcn_mfma_f32_32x32x16_bf16(wf[ks], xf, acc, 0, 0, 0);
        }
    } else {
        #pragma unroll
        for (int ks = 0; ks < 16; ++ks) {
            const bf8 xf = *(const bf8*)&xs[l5][(((ks * 2 + hi) ^ l5) & 31) * 8];
            acc = __builtin_amdgcn_mfma_f32_32x32x16_bf16(xf, wf[ks], acc, 0, 0, 0);
        }
    }

    const float QSCALE = 0.18033688011112042f;   // 0.125 * log2(e)
    if (mat == 0) {
        f4 b4[4];
        #pragma unroll
        for (int j = 0; j < 4; ++j)
            b4[j] = *(const f4*)&bq[head * 64 + d32 * 32 + j * 8 + 4 * hi];
        #pragma unroll
        for (int r = 0; r < 16; ++r) acc[r] = (acc[r] + b4[r >> 2][r & 3]) * QSCALE;
    } else if (mat == 1) {
        f4 b4[4];
        #pragma unroll
        for (int j = 0; j < 4; ++j)
            b4[j] = *(const f4*)&bk[head * 64 + d32 * 32 + j * 8 + 4 * hi];
        #pragma unroll
        for (int r = 0; r < 16; ++r) acc[r] += b4[r >> 2][r & 3];
    } else {
        const float bn = bv[head * 64 + d32 * 32 + l5];
        #pragma unroll
        for (int r = 0; r < 16; ++r) acc[r] += bn;
    }

    unsigned wd[8];
    #pragma unroll
    for (int i = 0; i < 8; ++i) wd[i] = pack2(acc[2 * i], acc[2 * i + 1]);
    const unsigned e0 = (unsigned)__shfl_xor((int)(hi ? wd[0] : wd[2]), 32, 64);
    const unsigned e1 = (unsigned)__shfl_xor((int)(hi ? wd[1] : wd[3]), 32, 64);
    const unsigned e2 = (unsigned)__shfl_xor((int)(hi ? wd[4] : wd[6]), 32, 64);
    const unsigned e3 = (unsigned)__shfl_xor((int)(hi ? wd[5] : wd[7]), 32, 64);
    union { unsigned u[4]; bf8 v; } fa, fb;
    if (hi == 0) {
        fa.u[0] = wd[0]; fa.u[1] = wd[1]; fa.u[2] = e0; fa.u[3] = e1;
        fb.u[0] = wd[4]; fb.u[1] = wd[5]; fb.u[2] = e2; fb.u[3] = e3;
    } else {
        fa.u[0] = e0; fa.u[1] = e1; fa.u[2] = wd[2]; fa.u[3] = wd[3];
        fb.u[0] = e2; fb.u[1] = e3; fb.u[2] = wd[6]; fb.u[3] = wd[7];
    }

    const int hd = bidx * NH + head;
    if (mat == 0) {
        __hip_bfloat16* qb = qfrag + (size_t)hd * QFRAG_PER_HEAD;
        *(bf8*)&qb[((size_t)(stl * 6 + d32 * 2 + 0) * 64 + lane) * 8] = fa.v;
        *(bf8*)&qb[((size_t)(stl * 6 + d32 * 2 + 1) * 64 + lane) * 8] = fb.v;
    } else if (mat == 1) {
        __hip_bfloat16* kb = kfrag + (size_t)hd * KFRAG_PER_HEAD;
        *(bf8*)&kb[((size_t)(tkv * 12 + d32 * 4 + hs) * 64 + lane) * 8] = fa.v;
        *(bf8*)&kb[((size_t)(tkv * 12 + d32 * 4 + 2 + hs) * 64 + lane) * 8] = fb.v;
    } else {
        __hip_bfloat16* vb = vfrag + (size_t)hd * VFRAG_PER_HEAD;
        const int ja = ((stl * 2 + 0) & 3) * 2 + d32;
        const int jb = ((stl * 2 + 1) & 3) * 2 + d32;
        *(bf8*)&vb[((size_t)(tkv * 8 + ja) * 64 + lane) * 8] = fa.v;
        *(bf8*)&vb[((size_t)(tkv * 8 + jb) * 64 + lane) * 8] = fb.v;
    }

    if (grp == 0) {
        const int hh = w;
        const int hd2 = bidx * NH + hh;
        __hip_bfloat16* qb = qfrag + (size_t)hd2 * QFRAG_PER_HEAD;
        __hip_bfloat16* kb = kfrag + (size_t)hd2 * KFRAG_PER_HEAD;
        u4v z; z[0] = 0; z[1] = 0; z[2] = 0; z[3] = 0;
        *(u4v*)&qb[((size_t)(stl * 6 + 4) * 64 + lane) * 8] = z;
        *(u4v*)&qb[((size_t)(stl * 6 + 5) * 64 + lane) * 8] = z;
        *(u4v*)&kb[((size_t)(tkv * 12 + 8 + hs) * 64 + lane) * 8] = z;
        *(u4v*)&kb[((size_t)(tkv * 12 + 10 + hs) * 64 + lane) * 8] = z;
        asm volatile("s_waitcnt vmcnt(0)" ::: "memory");
        if (hi == 0) {
            const int cg = gid[codons[bidx * SS + stl * 32 + l5] & 63];
            const float bl2e = *betaP;
            const int lt = ((cg >> 3) & 1) * 32 + l5;
            qb[((size_t)(stl * 6 + 4 + (cg >> 4)) * 64 + lt) * 8 + (cg & 7)] =
                __float2bfloat16(bl2e);
            kb[((size_t)(tkv * 12 + 8 + (cg >> 4) * 2 + hs) * 64 + lt) * 8 + (cg & 7)] =
                __float2bfloat16(1.0f);
        }
    }
}

// ---------------------------------------------------------------------------
// Flash attention: R8/R10 schedule but staging via global_load_lds (direct
// DMA to LDS: no staging VGPRs, no ds_write issue). Total regs/wave targets
// the <=128 bucket -> 4 waves/SIMD. Grid 1024 (KV quarters), 4 blocks/CU
// (LDS exactly 40960B). 4 bf16 partials merged in out_proj.
// ---------------------------------------------------------------------------
__global__ __launch_bounds__(256, 4)
void attn_kernel(const __hip_bfloat16* __restrict__ qfrag,
                 const __hip_bfloat16* __restrict__ kfrag,
                 const __hip_bfloat16* __restrict__ vfrag,
                 __hip_bfloat16* __restrict__ po0,
                 __hip_bfloat16* __restrict__ po1,
                 __hip_bfloat16* __restrict__ po2,
                 __hip_bfloat16* __restrict__ po3,
                 float* __restrict__ ls0, float* __restrict__ ls1,
                 float* __restrict__ ls2, float* __restrict__ ls3)
{
    const int bid = blockIdx.x;           // 1024 blocks
    const int bh = bid & 7;               // XCD-pinned (b,h)
    const int b = bh >> 2, h = bh & 3;
    const int quarter = (bid >> 3) & 3;
    const int qg = bid >> 5;              // 0..31 -> rows [qg*128, +128)
    const int tid = threadIdx.x;
    const int w = tid >> 6;               // wave -> 32-row q-subtile
    const int lane = tid & 63;
    const int q5 = lane & 31;
    const int hi = lane >> 5;

    __shared__ __align__(16) char smem[40960];   // 2 x 20KB KV tile; epilogue overlay

    const char* kT = (const char*)(kfrag + (size_t)(b * NH + h) * KFRAG_PER_HEAD);
    const char* vT = (const char*)(vfrag + (size_t)(b * NH + h) * VFRAG_PER_HEAD);

    // ---- Q fragments: wave w owns stile qg*4+w
    const int stl = qg * 4 + w;
    const __hip_bfloat16* qb = qfrag + (size_t)(b * NH + h) * QFRAG_PER_HEAD
                               + ((size_t)stl * 6 * 64 + lane) * 8;
    bf8 qf[6];
    #pragma unroll
    for (int ks = 0; ks < 6; ++ks) qf[ks] = *(const bf8*)&qb[ks * 512];

    f16v oacc0, oacc1;
    #pragma unroll
    for (int r = 0; r < 16; ++r) { oacc0[r] = 0.0f; oacc1[r] = 0.0f; }
    float lrun = 0.0f;

    const int w5 = w * 5;                 // this wave stages chunks w5..w5+4 (of 20)
    const int tt0 = quarter * 16;

    // DMA stage: src per-lane, LDS dest wave-uniform base + lane*16 (HW rule)
    auto stage = [&](int buf, int t) {
        const int tt = tt0 + t;
        #pragma unroll
        for (int c = 0; c < 5; ++c) {
            const int id = w5 + c;
            const char* src = (id < 12)
                ? kT + (size_t)tt * 12288 + (size_t)id * 1024
                : vT + (size_t)tt * 8192 + (size_t)(id - 12) * 1024;
            __builtin_amdgcn_global_load_lds(
                (const __attribute__((address_space(1))) unsigned int*)(src + lane * 16),
                (__attribute__((address_space(3))) unsigned int*)(smem + buf * 20480 + id * 1024),
                16, 0, 0);
        }
    };

    stage(0, 0);
    __syncthreads();                       // vmcnt(0) drain emitted by compiler

    int cur = 0;
    #pragma unroll 1
    for (int t = 0; t < 16; ++t) {
        if (t + 1 < 16) stage(cur ^ 1, t + 1);   // in-flight under compute

        const char* kb = smem + cur * 20480 + lane * 16;

        // ---- QK^T (swapped): D[key][q]
        f16v sA, sB;
        #pragma unroll
        for (int r = 0; r < 16; ++r) { sA[r] = 0.0f; sB[r] = 0.0f; }
        __builtin_amdgcn_s_setprio(1);
        #pragma unroll
        for (int ks = 0; ks < 6; ++ks) {
            const bf8 k0 = *(const bf8*)(kb + (2 * ks) * 1024);
            const bf8 k1 = *(const bf8*)(kb + (2 * ks + 1) * 1024);
            sA = __builtin_amdgcn_mfma_f32_32x32x16_bf16(k0, qf[ks], sA, 0, 0, 0);
            sB = __builtin_amdgcn_mfma_f32_32x32x16_bf16(k1, qf[ks], sB, 0, 0, 0);
        }
        __builtin_amdgcn_s_setprio(0);

        // ---- p = 2^s
        float ls = 0.0f;
        #pragma unroll
        for (int r = 0; r < 16; ++r) { sA[r] = fast_exp2(sA[r]); ls += sA[r]; }
        #pragma unroll
        for (int r = 0; r < 16; ++r) { sB[r] = fast_exp2(sB[r]); ls += sB[r]; }
        lrun += ls;

        // ---- cvt_pk pack-exchange -> PV B fragments
        unsigned dwv[2][4][2];
        #pragma unroll
        for (int j = 0; j < 4; ++j)
            #pragma unroll
            for (int c = 0; c < 2; ++c) {
                dwv[0][j][c] = cvtpk(sA[j * 4 + 2 * c], sA[j * 4 + 2 * c + 1]);
                dwv[1][j][c] = cvtpk(sB[j * 4 + 2 * c], sB[j * 4 + 2 * c + 1]);
            }
        unsigned rc[2][2][2];
        #pragma unroll
        for (int t2 = 0; t2 < 2; ++t2)
            #pragma unroll
            for (int k1 = 0; k1 < 2; ++k1)
                #pragma unroll
                for (int c = 0; c < 2; ++c) {
                    const unsigned snd = hi ? dwv[t2][2 * k1][c] : dwv[t2][2 * k1 + 1][c];
                    rc[t2][k1][c] = (unsigned)__shfl_xor((int)snd, 32, 64);
                }
        bf8 pfv[4];
        #pragma unroll
        for (int ks = 0; ks < 4; ++ks) {
            const int t2 = ks >> 1, k1 = ks & 1;
            union { unsigned u[4]; bf8 v; } pu;
            pu.u[0] = hi ? rc[t2][k1][0] : dwv[t2][2 * k1][0];
            pu.u[1] = hi ? rc[t2][k1][1] : dwv[t2][2 * k1][1];
            pu.u[2] = hi ? dwv[t2][2 * k1 + 1][0] : rc[t2][k1][0];
            pu.u[3] = hi ? dwv[t2][2 * k1 + 1][1] : rc[t2][k1][1];
            pfv[ks] = pu.v;
        }

        // ---- PV
        __builtin_amdgcn_s_setprio(1);
        #pragma unroll
        for (int ks = 0; ks < 4; ++ks) {
            const bf8 v0 = *(const bf8*)(kb + (12 + 2 * ks) * 1024);
            const bf8 v1 = *(const bf8*)(kb + (13 + 2 * ks) * 1024);
            oacc0 = __builtin_amdgcn_mfma_f32_32x32x16_bf16(v0, pfv[ks], oacc0, 0, 0, 0);
            oacc1 = __builtin_amdgcn_mfma_f32_32x32x16_bf16(v1, pfv[ks], oacc1, 0, 0, 0);
        }
        __builtin_amdgcn_s_setprio(0);

        __syncthreads();                   // drains stage(t+1) DMA; swap buffers
        cur ^= 1;
    }

    // ---- epilogue: partials -> LDS overlay (pitch 66) -> coalesced bf16 dump
    const float ltot = lrun + __shfl_xor(lrun, 32, 64);
    float* osh = (float*)smem;                 // 128 rows x 66 floats = 33792 B
    float* lsh = (float*)(smem + 33792);       // 128 floats
    #pragma unroll
    for (int r = 0; r < 16; ++r) {
        const int d = (r & 3) + 8 * (r >> 2) + 4 * hi;
        osh[(w * 32 + q5) * 66 + d] = oacc0[r];
        osh[(w * 32 + q5) * 66 + 32 + d] = oacc1[r];
    }
    if (hi == 0) lsh[w * 32 + q5] = ltot;
    __syncthreads();

    __hip_bfloat16* pob = (quarter == 0) ? po0 : (quarter == 1) ? po1
                        : (quarter == 2) ? po2 : po3;
    float* lsb = (quarter == 0) ? ls0 : (quarter == 1) ? ls1
               : (quarter == 2) ? ls2 : ls3;
    const int row = tid >> 1;
    const int dh = (tid & 1) * 32;
    const float* src = &osh[row * 66 + dh];
    __hip_bfloat16* dst = pob + ((size_t)(b * SS + qg * 128 + row) * HID + h * HD + dh);
    #pragma unroll
    for (int j = 0; j < 4; ++j) {
        const f4 x0 = *(const f4*)&src[j * 8];
        const f4 x1 = *(const f4*)&src[j * 8 + 4];
        union { unsigned u[4]; bf8 v; } o;
        o.u[0] = pack2(x0[0], x0[1]); o.u[1] = pack2(x0[2], x0[3]);
        o.u[2] = pack2(x1[0], x1[1]); o.u[3] = pack2(x1[2], x1[3]);
        *(bf8*)&dst[j * 8] = o.v;
    }
    if (tid < 128) lsb[(size_t)(b * SS + qg * 128 + tid) * 4 + h] = lsh[tid];
}

// ---------------------------------------------------------------------------
// Output projection via MFMA; merges the four KV-quarter partials in staging.
// ---------------------------------------------------------------------------
__global__ __launch_bounds__(256)
void out_proj_kernel(const __hip_bfloat16* __restrict__ po0,
                     const __hip_bfloat16* __restrict__ po1,
                     const __hip_bfloat16* __restrict__ po2,
                     const __hip_bfloat16* __restrict__ po3,
                     const float* __restrict__ ls0, const float* __restrict__ ls1,
                     const float* __restrict__ ls2, const float* __restrict__ ls3,
                     const __hip_bfloat16* __restrict__ wpk,
                     const float* __restrict__ bo, float* __restrict__ out)
{
    const int bid = blockIdx.x;
    const int stile = bid >> 1, grp = bid & 1;
    const int tid = threadIdx.x;
    const int w = tid >> 6, lane = tid & 63, hi = lane >> 5, l5 = lane & 31;

    __shared__ __hip_bfloat16 xs[32][256];
    {
        const int r0 = tid >> 5, c = tid & 31;
        #pragma unroll
        for (int it = 0; it < 4; ++it) {
            const int row = r0 + it * 8;
            const size_t srow = (size_t)stile * 32 + row;
            const int head = c >> 3;
            const float inv = 1.0f / (ls0[srow * 4 + head] + ls1[srow * 4 + head]
                                    + ls2[srow * 4 + head] + ls3[srow * 4 + head]);
            union { bf8 v; unsigned u[4]; } a0, a1, a2, a3;
            a0.v = *(const bf8*)&po0[srow * 256 + c * 8];
            a1.v = *(const bf8*)&po1[srow * 256 + c * 8];
            a2.v = *(const bf8*)&po2[srow * 256 + c * 8];
            a3.v = *(const bf8*)&po3[srow * 256 + c * 8];
            union { unsigned u[4]; bf8 v; } o;
            #pragma unroll
            for (int i = 0; i < 4; ++i) {
                const float lo = __uint_as_float(a0.u[i] << 16)
                               + __uint_as_float(a1.u[i] << 16)
                               + __uint_as_float(a2.u[i] << 16)
                               + __uint_as_float(a3.u[i] << 16);
                const float hv = __uint_as_float(a0.u[i] & 0xffff0000u)
                               + __uint_as_float(a1.u[i] & 0xffff0000u)
                               + __uint_as_float(a2.u[i] & 0xffff0000u)
                               + __uint_as_float(a3.u[i] & 0xffff0000u);
                o.u[i] = pack2(lo * inv, hv * inv);
            }
            *(bf8*)&xs[row][((c ^ row) & 31) * 8] = o.v;
        }
    }
    __syncthreads();

    const int nt = grp * 4 + w;           // 0..7
    const __hip_bfloat16* wb = wpk + (size_t)((3 * 8 + nt) * 16) * 512 + (size_t)lane * 8;
    bf8 wf[16];
    #pragma unroll
    for (int ks = 0; ks < 16; ++ks) wf[ks] = *(const bf8*)&wb[ks * 512];

    f16v acc;
    #pragma unroll
    for (int r = 0; r < 16; ++r) acc[r] = 0.0f;
    #pragma unroll
    for (int ks = 0; ks < 16; ++ks) {
        const bf8 xf = *(const bf8*)&xs[l5][(((ks * 2 + hi) ^ l5) & 31) * 8];
        acc = __builtin_amdgcn_mfma_f32_32x32x16_bf16(xf, wf[ks], acc, 0, 0, 0);
    }

    const float bn = bo[nt * 32 + l5];
    #pragma unroll
    for (int r = 0; r < 16; ++r) {
        const int sloc = (r & 3) + 8 * (r >> 2) + 4 * hi;
        out[(size_t)(stile * 32 + sloc) * HID + nt * 32 + l5] = acc[r] + bn;
    }
}

extern "C" void kernel_launch(void* const* d_in, const int* in_sizes, int n_in,
                              void* d_out, int out_size, void* d_ws, size_t ws_size,
                              hipStream_t stream)
{
    (void)in_sizes; (void)n_in; (void)out_size; (void)ws_size;
    const float* x        = (const float*)d_in[0];
    const int*   codons   = (const int*)d_in[1];
    const float* syn_bias = (const float*)d_in[2];
    const float* wq = (const float*)d_in[3];
    const float* bq = (const float*)d_in[4];
    const float* wk = (const float*)d_in[5];
    const float* bk = (const float*)d_in[6];
    const float* wv = (const float*)d_in[7];
    const float* bv = (const float*)d_in[8];
    const float* wo = (const float*)d_in[9];
    const float* bo = (const float*)d_in[10];
    float* out = (float*)d_out;

    char* ws = (char*)d_ws;
    int*   gid   = (int*)(ws);                                  // 256 B
    float* betaP = (float*)(ws + 256);                          // 4 B
    __hip_bfloat16* wpk   = (__hip_bfloat16*)(ws + 4096);       // 512 KB
    __hip_bfloat16* qfrag = (__hip_bfloat16*)(ws + (size_t)1048576u);    // 6.29 MB
    __hip_bfloat16* kfrag = (__hip_bfloat16*)(ws + (size_t)7340032u);    // 6.29 MB
    __hip_bfloat16* vfrag = (__hip_bfloat16*)(ws + (size_t)13631488u);   // 4.19 MB
    __hip_bfloat16* po0   = (__hip_bfloat16*)(ws + (size_t)17825792u);   // 4.19 MB
    __hip_bfloat16* po1   = (__hip_bfloat16*)(ws + (size_t)22020096u);   // 4.19 MB
    __hip_bfloat16* po2   = (__hip_bfloat16*)(ws + (size_t)26214400u);   // 4.19 MB
    __hip_bfloat16* po3   = (__hip_bfloat16*)(ws + (size_t)30408704u);   // 4.19 MB
    float* ls0            = (float*)(ws + (size_t)34603008u);            // 128 KB
    float* ls1            = (float*)(ws + (size_t)34734080u);            // 128 KB
    float* ls2            = (float*)(ws + (size_t)34865152u);            // 128 KB
    float* ls3            = (float*)(ws + (size_t)34996224u);            // 128 KB

    setup_kernel<<<1, 64, 0, stream>>>(syn_bias, gid, betaP);
    pack_w_kernel<<<128, 256, 0, stream>>>(wq, wk, wv, wo, wpk);
    qkv_mfma_kernel<<<1536, 256, 0, stream>>>(x, wpk, bq, bk, bv, codons, gid, betaP,
                                              qfrag, kfrag, vfrag);
    attn_kernel<<<1024, 256, 0, stream>>>(qfrag, kfrag, vfrag,
                                          po0, po1, po2, po3, ls0, ls1, ls2, ls3);
    out_proj_kernel<<<512, 256, 0, stream>>>(po0, po1, po2, po3,
                                             ls0, ls1, ls2, ls3, wpk, bo, out);
}

// Round 14
// 84.742 us; speedup vs baseline: 1.0593x; 1.0593x over previous
//
#include <hip/hip_runtime.h>
#include <hip/hip_bf16.h>

#define NH 4
#define HD 64
#define HID 256
#define SS 4096

#define QFRAG_PER_HEAD (128 * 6 * 64 * 8)   // 393216 elems
#define KFRAG_PER_HEAD (64 * 12 * 64 * 8)   // 393216 elems
#define VFRAG_PER_HEAD (64 * 8 * 64 * 8)    // 262144 elems

typedef float f4 __attribute__((ext_vector_type(4)));
typedef float f16v __attribute__((ext_vector_type(16)));
typedef short bf8 __attribute__((ext_vector_type(8)));   // 8 bf16
typedef unsigned int u4v __attribute__((ext_vector_type(4)));

static __device__ __forceinline__ float fast_exp2(float x) {
#if __has_builtin(__builtin_amdgcn_exp2f)
    return __builtin_amdgcn_exp2f(x);
#else
    float r; asm("v_exp_f32 %0, %1" : "=v"(r) : "v"(x)); return r;
#endif
}

static __device__ __forceinline__ unsigned pack2(float a, float b) {
    unsigned ua = (unsigned)__bfloat16_as_ushort(__float2bfloat16(a));
    unsigned ub = (unsigned)__bfloat16_as_ushort(__float2bfloat16(b));
    return ua | (ub << 16);
}

// single-instruction packed f32x2 -> bf16x2 (T12; no builtin on gfx950)
static __device__ __forceinline__ unsigned cvtpk(float a, float b) {
    unsigned r;
    asm("v_cvt_pk_bf16_f32 %0, %1, %2" : "=v"(r) : "v"(a), "v"(b));
    return r;
}

// ---------------------------------------------------------------------------
// Pack wq/wk/wv/wo into MFMA fragment-major bf16. Block 0 additionally
// derives the codon->group-id map + beta*log2e (folded former setup_kernel;
// consumers are in later launches, so ordering is guaranteed).
// ---------------------------------------------------------------------------
__global__ __launch_bounds__(256)
void pack_w_kernel(const float* __restrict__ wq, const float* __restrict__ wk,
                   const float* __restrict__ wv, const float* __restrict__ wo,
                   const float* __restrict__ syn,
                   int* __restrict__ gid, float* __restrict__ betaP,
                   __hip_bfloat16* __restrict__ wpk)
{
    if (blockIdx.x == 0 && threadIdx.x < 64) {
        const int lane = threadIdx.x;          // 0..63
        int rep = 64;
        for (int j = 63; j >= 0; --j)
            if (syn[lane * 64 + j] != 0.0f) rep = j;
        if (rep == 64) rep = lane;
        unsigned long long m = __ballot(rep == lane);
        int id = (int)__popcll(m & ((2ull << rep) - 1ull)) - 1;
        if (id < 0) id = 0;
        gid[lane] = id;                                 // 0..20
        if (lane == 0) *betaP = syn[0] * 1.44269504088896f;
    }

    const int t = blockIdx.x * 256 + threadIdx.x;   // 0..32767
    const int mat = t >> 13;
    const int r = t & 8191;
    const int dt = r >> 10, ks = (r >> 6) & 15, lane = r & 63;
    const float* w = (mat == 0) ? wq : (mat == 1) ? wk : (mat == 2) ? wv : wo;
    const int row = dt * 32 + (lane & 31);
    const int col = ks * 16 + (lane >> 5) * 8;
    const f4 a = *(const f4*)&w[(size_t)row * 256 + col];
    const f4 b = *(const f4*)&w[(size_t)row * 256 + col + 4];
    union { unsigned u[4]; bf8 v; } o;
    o.u[0] = pack2(a[0], a[1]); o.u[1] = pack2(a[2], a[3]);
    o.u[2] = pack2(b[0], b[1]); o.u[3] = pack2(b[2], b[3]);
    *(bf8*)&wpk[(size_t)t * 8] = o.v;
}

// ---------------------------------------------------------------------------
// QKV projection via MFMA (unchanged from R6).
// ---------------------------------------------------------------------------
__global__ __launch_bounds__(256)
void qkv_mfma_kernel(const float* __restrict__ x,
                     const __hip_bfloat16* __restrict__ wpk,
                     const float* __restrict__ bq, const float* __restrict__ bk,
                     const float* __restrict__ bv,
                     const int* __restrict__ codons,
                     const int* __restrict__ gid, const float* __restrict__ betaP,
                     __hip_bfloat16* __restrict__ qfrag,
                     __hip_bfloat16* __restrict__ kfrag,
                     __hip_bfloat16* __restrict__ vfrag)
{
    const int bid = blockIdx.x;
    const int stile = bid / 6;            // 0..255
    const int grp = bid % 6;
    const int tid = threadIdx.x;
    const int w = tid >> 6, lane = tid & 63, hi = lane >> 5, l5 = lane & 31;

    const int bidx = stile >> 7;
    const int stl = stile & 127;
    const int hs = stl & 1, tkv = stl >> 1;

    __shared__ __hip_bfloat16 xs[32][256];

    {
        const int r0 = tid >> 5, c = tid & 31;
        #pragma unroll
        for (int it = 0; it < 4; ++it) {
            const int row = r0 + it * 8;
            const f4 a = *(const f4*)&x[(size_t)(stile * 32 + row) * HID + c * 8];
            const f4 b2 = *(const f4*)&x[(size_t)(stile * 32 + row) * HID + c * 8 + 4];
            union { unsigned u[4]; bf8 v; } o;
            o.u[0] = pack2(a[0], a[1]); o.u[1] = pack2(a[2], a[3]);
            o.u[2] = pack2(b2[0], b2[1]); o.u[3] = pack2(b2[2], b2[3]);
            *(bf8*)&xs[row][((c ^ row) & 31) * 8] = o.v;
        }
    }
    __syncthreads();

    const int t24 = grp * 4 + w;          // 0..23
    const int mat = t24 >> 3;             // 0=q 1=k 2=v
    const int dt = t24 & 7;
    const int head = dt >> 1, d32 = dt & 1;

    const __hip_bfloat16* wb = wpk + (size_t)((mat * 8 + dt) * 16) * 512 + (size_t)lane * 8;
    bf8 wf[16];
    #pragma unroll
    for (int ks = 0; ks < 16; ++ks) wf[ks] = *(const bf8*)&wb[ks * 512];

    f16v acc;
    #pragma unroll
    for (int r = 0; r < 16; ++r) acc[r] = 0.0f;

    if (mat < 2) {
        #pragma unroll
        for (int ks = 0; ks < 16; ++ks) {
            const bf8 xf = *(const bf8*)&xs[l5][(((ks * 2 + hi) ^ l5) & 31) * 8];
            acc = __builtin_amdgcn_mfma_f32_32x32x16_bf16(wf[ks], xf, acc, 0, 0, 0);
        }
    } else {
        #pragma unroll
        for (int ks = 0; ks < 16; ++ks) {
            const bf8 xf = *(const bf8*)&xs[l5][(((ks * 2 + hi) ^ l5) & 31) * 8];
            acc = __builtin_amdgcn_mfma_f32_32x32x16_bf16(xf, wf[ks], acc, 0, 0, 0);
        }
    }

    const float QSCALE = 0.18033688011112042f;   // 0.125 * log2(e)
    if (mat == 0) {
        f4 b4[4];
        #pragma unroll
        for (int j = 0; j < 4; ++j)
            b4[j] = *(const f4*)&bq[head * 64 + d32 * 32 + j * 8 + 4 * hi];
        #pragma unroll
        for (int r = 0; r < 16; ++r) acc[r] = (acc[r] + b4[r >> 2][r & 3]) * QSCALE;
    } else if (mat == 1) {
        f4 b4[4];
        #pragma unroll
        for (int j = 0; j < 4; ++j)
            b4[j] = *(const f4*)&bk[head * 64 + d32 * 32 + j * 8 + 4 * hi];
        #pragma unroll
        for (int r = 0; r < 16; ++r) acc[r] += b4[r >> 2][r & 3];
    } else {
        const float bn = bv[head * 64 + d32 * 32 + l5];
        #pragma unroll
        for (int r = 0; r < 16; ++r) acc[r] += bn;
    }

    unsigned wd[8];
    #pragma unroll
    for (int i = 0; i < 8; ++i) wd[i] = pack2(acc[2 * i], acc[2 * i + 1]);
    const unsigned e0 = (unsigned)__shfl_xor((int)(hi ? wd[0] : wd[2]), 32, 64);
    const unsigned e1 = (unsigned)__shfl_xor((int)(hi ? wd[1] : wd[3]), 32, 64);
    const unsigned e2 = (unsigned)__shfl_xor((int)(hi ? wd[4] : wd[6]), 32, 64);
    const unsigned e3 = (unsigned)__shfl_xor((int)(hi ? wd[5] : wd[7]), 32, 64);
    union { unsigned u[4]; bf8 v; } fa, fb;
    if (hi == 0) {
        fa.u[0] = wd[0]; fa.u[1] = wd[1]; fa.u[2] = e0; fa.u[3] = e1;
        fb.u[0] = wd[4]; fb.u[1] = wd[5]; fb.u[2] = e2; fb.u[3] = e3;
    } else {
        fa.u[0] = e0; fa.u[1] = e1; fa.u[2] = wd[2]; fa.u[3] = wd[3];
        fb.u[0] = e2; fb.u[1] = e3; fb.u[2] = wd[6]; fb.u[3] = wd[7];
    }

    const int hd = bidx * NH + head;
    if (mat == 0) {
        __hip_bfloat16* qb = qfrag + (size_t)hd * QFRAG_PER_HEAD;
        *(bf8*)&qb[((size_t)(stl * 6 + d32 * 2 + 0) * 64 + lane) * 8] = fa.v;
        *(bf8*)&qb[((size_t)(stl * 6 + d32 * 2 + 1) * 64 + lane) * 8] = fb.v;
    } else if (mat == 1) {
        __hip_bfloat16* kb = kfrag + (size_t)hd * KFRAG_PER_HEAD;
        *(bf8*)&kb[((size_t)(tkv * 12 + d32 * 4 + hs) * 64 + lane) * 8] = fa.v;
        *(bf8*)&kb[((size_t)(tkv * 12 + d32 * 4 + 2 + hs) * 64 + lane) * 8] = fb.v;
    } else {
        __hip_bfloat16* vb = vfrag + (size_t)hd * VFRAG_PER_HEAD;
        const int ja = ((stl * 2 + 0) & 3) * 2 + d32;
        const int jb = ((stl * 2 + 1) & 3) * 2 + d32;
        *(bf8*)&vb[((size_t)(tkv * 8 + ja) * 64 + lane) * 8] = fa.v;
        *(bf8*)&vb[((size_t)(tkv * 8 + jb) * 64 + lane) * 8] = fb.v;
    }

    if (grp == 0) {
        const int hh = w;
        const int hd2 = bidx * NH + hh;
        __hip_bfloat16* qb = qfrag + (size_t)hd2 * QFRAG_PER_HEAD;
        __hip_bfloat16* kb = kfrag + (size_t)hd2 * KFRAG_PER_HEAD;
        u4v z; z[0] = 0; z[1] = 0; z[2] = 0; z[3] = 0;
        *(u4v*)&qb[((size_t)(stl * 6 + 4) * 64 + lane) * 8] = z;
        *(u4v*)&qb[((size_t)(stl * 6 + 5) * 64 + lane) * 8] = z;
        *(u4v*)&kb[((size_t)(tkv * 12 + 8 + hs) * 64 + lane) * 8] = z;
        *(u4v*)&kb[((size_t)(tkv * 12 + 10 + hs) * 64 + lane) * 8] = z;
        asm volatile("s_waitcnt vmcnt(0)" ::: "memory");
        if (hi == 0) {
            const int cg = gid[codons[bidx * SS + stl * 32 + l5] & 63];
            const float bl2e = *betaP;
            const int lt = ((cg >> 3) & 1) * 32 + l5;
            qb[((size_t)(stl * 6 + 4 + (cg >> 4)) * 64 + lt) * 8 + (cg & 7)] =
                __float2bfloat16(bl2e);
            kb[((size_t)(tkv * 12 + 8 + (cg >> 4) * 2 + hs) * 64 + lt) * 8 + (cg & 7)] =
                __float2bfloat16(1.0f);
        }
    }
}

// ---------------------------------------------------------------------------
// Flash attention: R13 structure (global_load_lds staging, VGPR~64, grid
// 1024 KV-quarters) with (a) NO setprio — suspected to starve co-resident
// waves' VALU/LDS issue and block cross-wave pipe overlap (m190 analog);
// (b) v_permlane32_swap_b32 pack-exchange — one instr yields both output
// words, replacing 8 shfl + 32 cndmask per iter.
// ---------------------------------------------------------------------------
__global__ __launch_bounds__(256, 4)
void attn_kernel(const __hip_bfloat16* __restrict__ qfrag,
                 const __hip_bfloat16* __restrict__ kfrag,
                 const __hip_bfloat16* __restrict__ vfrag,
                 __hip_bfloat16* __restrict__ po0,
                 __hip_bfloat16* __restrict__ po1,
                 __hip_bfloat16* __restrict__ po2,
                 __hip_bfloat16* __restrict__ po3,
                 float* __restrict__ ls0, float* __restrict__ ls1,
                 float* __restrict__ ls2, float* __restrict__ ls3)
{
    const int bid = blockIdx.x;           // 1024 blocks
    const int bh = bid & 7;               // XCD-pinned (b,h)
    const int b = bh >> 2, h = bh & 3;
    const int quarter = (bid >> 3) & 3;
    const int qg = bid >> 5;              // 0..31 -> rows [qg*128, +128)
    const int tid = threadIdx.x;
    const int w = tid >> 6;               // wave -> 32-row q-subtile
    const int lane = tid & 63;
    const int q5 = lane & 31;
    const int hi = lane >> 5;

    __shared__ __align__(16) char smem[40960];   // 2 x 20KB KV tile; epilogue overlay

    const char* kT = (const char*)(kfrag + (size_t)(b * NH + h) * KFRAG_PER_HEAD);
    const char* vT = (const char*)(vfrag + (size_t)(b * NH + h) * VFRAG_PER_HEAD);

    // ---- Q fragments: wave w owns stile qg*4+w
    const int stl = qg * 4 + w;
    const __hip_bfloat16* qb = qfrag + (size_t)(b * NH + h) * QFRAG_PER_HEAD
                               + ((size_t)stl * 6 * 64 + lane) * 8;
    bf8 qf[6];
    #pragma unroll
    for (int ks = 0; ks < 6; ++ks) qf[ks] = *(const bf8*)&qb[ks * 512];

    f16v oacc0, oacc1;
    #pragma unroll
    for (int r = 0; r < 16; ++r) { oacc0[r] = 0.0f; oacc1[r] = 0.0f; }
    float lrun = 0.0f;

    const int w5 = w * 5;                 // this wave stages chunks w5..w5+4 (of 20)
    const int tt0 = quarter * 16;

    auto stage = [&](int buf, int t) {
        const int tt = tt0 + t;
        #pragma unroll
        for (int c = 0; c < 5; ++c) {
            const int id = w5 + c;
            const char* src = (id < 12)
                ? kT + (size_t)tt * 12288 + (size_t)id * 1024
                : vT + (size_t)tt * 8192 + (size_t)(id - 12) * 1024;
            __builtin_amdgcn_global_load_lds(
                (const __attribute__((address_space(1))) unsigned int*)(src + lane * 16),
                (__attribute__((address_space(3))) unsigned int*)(smem + buf * 20480 + id * 1024),
                16, 0, 0);
        }
    };

    stage(0, 0);
    __syncthreads();

    int cur = 0;
    #pragma unroll 1
    for (int t = 0; t < 16; ++t) {
        if (t + 1 < 16) stage(cur ^ 1, t + 1);   // in-flight under compute

        const char* kb = smem + cur * 20480 + lane * 16;

        // ---- QK^T (swapped): D[key][q]
        f16v sA, sB;
        #pragma unroll
        for (int r = 0; r < 16; ++r) { sA[r] = 0.0f; sB[r] = 0.0f; }
        #pragma unroll
        for (int ks = 0; ks < 6; ++ks) {
            const bf8 k0 = *(const bf8*)(kb + (2 * ks) * 1024);
            const bf8 k1 = *(const bf8*)(kb + (2 * ks + 1) * 1024);
            sA = __builtin_amdgcn_mfma_f32_32x32x16_bf16(k0, qf[ks], sA, 0, 0, 0);
            sB = __builtin_amdgcn_mfma_f32_32x32x16_bf16(k1, qf[ks], sB, 0, 0, 0);
        }

        // ---- p = 2^s
        float ls = 0.0f;
        #pragma unroll
        for (int r = 0; r < 16; ++r) { sA[r] = fast_exp2(sA[r]); ls += sA[r]; }
        #pragma unroll
        for (int r = 0; r < 16; ++r) { sB[r] = fast_exp2(sB[r]); ls += sB[r]; }
        lrun += ls;

        // ---- cvt_pk + permlane32_swap pack-exchange -> PV B fragments
        // For each (t2,k1,c): A=dwv[2k1][c], B=dwv[2k1+1][c]; after swap
        // A = u[c]  (lo: own 2k1 | hi: lo-partner's 2k1+1),
        // B = u[2+c](lo: hi-partner's 2k1 | hi: own 2k1+1).
        bf8 pfv[4];
        #pragma unroll
        for (int t2 = 0; t2 < 2; ++t2) {
            const f16v& s = t2 ? sB : sA;
            unsigned dwv[4][2];
            #pragma unroll
            for (int j = 0; j < 4; ++j)
                #pragma unroll
                for (int c = 0; c < 2; ++c)
                    dwv[j][c] = cvtpk(s[j * 4 + 2 * c], s[j * 4 + 2 * c + 1]);
            #pragma unroll
            for (int k1 = 0; k1 < 2; ++k1) {
                union { unsigned u[4]; bf8 v; } pu;
                #pragma unroll
                for (int c = 0; c < 2; ++c) {
                    unsigned a = dwv[2 * k1][c];
                    unsigned bch = dwv[2 * k1 + 1][c];
                    asm volatile("v_permlane32_swap_b32 %0, %1"
                                 : "+v"(a), "+v"(bch));
                    pu.u[c] = a;
                    pu.u[2 + c] = bch;
                }
                pfv[t2 * 2 + k1] = pu.v;
            }
        }

        // ---- PV
        #pragma unroll
        for (int ks = 0; ks < 4; ++ks) {
            const bf8 v0 = *(const bf8*)(kb + (12 + 2 * ks) * 1024);
            const bf8 v1 = *(const bf8*)(kb + (13 + 2 * ks) * 1024);
            oacc0 = __builtin_amdgcn_mfma_f32_32x32x16_bf16(v0, pfv[ks], oacc0, 0, 0, 0);
            oacc1 = __builtin_amdgcn_mfma_f32_32x32x16_bf16(v1, pfv[ks], oacc1, 0, 0, 0);
        }

        __syncthreads();                   // drains stage(t+1) DMA; swap buffers
        cur ^= 1;
    }

    // ---- epilogue: partials -> LDS overlay (pitch 66) -> coalesced bf16 dump
    const float ltot = lrun + __shfl_xor(lrun, 32, 64);
    float* osh = (float*)smem;                 // 128 rows x 66 floats = 33792 B
    float* lsh = (float*)(smem + 33792);       // 128 floats
    #pragma unroll
    for (int r = 0; r < 16; ++r) {
        const int d = (r & 3) + 8 * (r >> 2) + 4 * hi;
        osh[(w * 32 + q5) * 66 + d] = oacc0[r];
        osh[(w * 32 + q5) * 66 + 32 + d] = oacc1[r];
    }
    if (hi == 0) lsh[w * 32 + q5] = ltot;
    __syncthreads();

    __hip_bfloat16* pob = (quarter == 0) ? po0 : (quarter == 1) ? po1
                        : (quarter == 2) ? po2 : po3;
    float* lsb = (quarter == 0) ? ls0 : (quarter == 1) ? ls1
               : (quarter == 2) ? ls2 : ls3;
    const int row = tid >> 1;
    const int dh = (tid & 1) * 32;
    const float* src = &osh[row * 66 + dh];
    __hip_bfloat16* dst = pob + ((size_t)(b * SS + qg * 128 + row) * HID + h * HD + dh);
    #pragma unroll
    for (int j = 0; j < 4; ++j) {
        const f4 x0 = *(const f4*)&src[j * 8];
        const f4 x1 = *(const f4*)&src[j * 8 + 4];
        union { unsigned u[4]; bf8 v; } o;
        o.u[0] = pack2(x0[0], x0[1]); o.u[1] = pack2(x0[2], x0[3]);
        o.u[2] = pack2(x1[0], x1[1]); o.u[3] = pack2(x1[2], x1[3]);
        *(bf8*)&dst[j * 8] = o.v;
    }
    if (tid < 128) lsb[(size_t)(b * SS + qg * 128 + tid) * 4 + h] = lsh[tid];
}

// ---------------------------------------------------------------------------
// Output projection via MFMA; merges the four KV-quarter partials in staging.
// ---------------------------------------------------------------------------
__global__ __launch_bounds__(256)
void out_proj_kernel(const __hip_bfloat16* __restrict__ po0,
                     const __hip_bfloat16* __restrict__ po1,
                     const __hip_bfloat16* __restrict__ po2,
                     const __hip_bfloat16* __restrict__ po3,
                     const float* __restrict__ ls0, const float* __restrict__ ls1,
                     const float* __restrict__ ls2, const float* __restrict__ ls3,
                     const __hip_bfloat16* __restrict__ wpk,
                     const float* __restrict__ bo, float* __restrict__ out)
{
    const int bid = blockIdx.x;
    const int stile = bid >> 1, grp = bid & 1;
    const int tid = threadIdx.x;
    const int w = tid >> 6, lane = tid & 63, hi = lane >> 5, l5 = lane & 31;

    __shared__ __hip_bfloat16 xs[32][256];
    {
        const int r0 = tid >> 5, c = tid & 31;
        #pragma unroll
        for (int it = 0; it < 4; ++it) {
            const int row = r0 + it * 8;
            const size_t srow = (size_t)stile * 32 + row;
            const int head = c >> 3;
            const float inv = 1.0f / (ls0[srow * 4 + head] + ls1[srow * 4 + head]
                                    + ls2[srow * 4 + head] + ls3[srow * 4 + head]);
            union { bf8 v; unsigned u[4]; } a0, a1, a2, a3;
            a0.v = *(const bf8*)&po0[srow * 256 + c * 8];
            a1.v = *(const bf8*)&po1[srow * 256 + c * 8];
            a2.v = *(const bf8*)&po2[srow * 256 + c * 8];
            a3.v = *(const bf8*)&po3[srow * 256 + c * 8];
            union { unsigned u[4]; bf8 v; } o;
            #pragma unroll
            for (int i = 0; i < 4; ++i) {
                const float lo = __uint_as_float(a0.u[i] << 16)
                               + __uint_as_float(a1.u[i] << 16)
                               + __uint_as_float(a2.u[i] << 16)
                               + __uint_as_float(a3.u[i] << 16);
                const float hv = __uint_as_float(a0.u[i] & 0xffff0000u)
                               + __uint_as_float(a1.u[i] & 0xffff0000u)
                               + __uint_as_float(a2.u[i] & 0xffff0000u)
                               + __uint_as_float(a3.u[i] & 0xffff0000u);
                o.u[i] = pack2(lo * inv, hv * inv);
            }
            *(bf8*)&xs[row][((c ^ row) & 31) * 8] = o.v;
        }
    }
    __syncthreads();

    const int nt = grp * 4 + w;           // 0..7
    const __hip_bfloat16* wb = wpk + (size_t)((3 * 8 + nt) * 16) * 512 + (size_t)lane * 8;
    bf8 wf[16];
    #pragma unroll
    for (int ks = 0; ks < 16; ++ks) wf[ks] = *(const bf8*)&wb[ks * 512];

    f16v acc;
    #pragma unroll
    for (int r = 0; r < 16; ++r) acc[r] = 0.0f;
    #pragma unroll
    for (int ks = 0; ks < 16; ++ks) {
        const bf8 xf = *(const bf8*)&xs[l5][(((ks * 2 + hi) ^ l5) & 31) * 8];
        acc = __builtin_amdgcn_mfma_f32_32x32x16_bf16(xf, wf[ks], acc, 0, 0, 0);
    }

    const float bn = bo[nt * 32 + l5];
    #pragma unroll
    for (int r = 0; r < 16; ++r) {
        const int sloc = (r & 3) + 8 * (r >> 2) + 4 * hi;
        out[(size_t)(stile * 32 + sloc) * HID + nt * 32 + l5] = acc[r] + bn;
    }
}

extern "C" void kernel_launch(void* const* d_in, const int* in_sizes, int n_in,
                              void* d_out, int out_size, void* d_ws, size_t ws_size,
                              hipStream_t stream)
{
    (void)in_sizes; (void)n_in; (void)out_size; (void)ws_size;
    const float* x        = (const float*)d_in[0];
    const int*   codons   = (const int*)d_in[1];
    const float* syn_bias = (const float*)d_in[2];
    const float* wq = (const float*)d_in[3];
    const float* bq = (const float*)d_in[4];
    const float* wk = (const float*)d_in[5];
    const float* bk = (const float*)d_in[6];
    const float* wv = (const float*)d_in[7];
    const float* bv = (const float*)d_in[8];
    const float* wo = (const float*)d_in[9];
    const float* bo = (const float*)d_in[10];
    float* out = (float*)d_out;

    char* ws = (char*)d_ws;
    int*   gid   = (int*)(ws);                                  // 256 B
    float* betaP = (float*)(ws + 256);                          // 4 B
    __hip_bfloat16* wpk   = (__hip_bfloat16*)(ws + 4096);       // 512 KB
    __hip_bfloat16* qfrag = (__hip_bfloat16*)(ws + (size_t)1048576u);    // 6.29 MB
    __hip_bfloat16* kfrag = (__hip_bfloat16*)(ws + (size_t)7340032u);    // 6.29 MB
    __hip_bfloat16* vfrag = (__hip_bfloat16*)(ws + (size_t)13631488u);   // 4.19 MB
    __hip_bfloat16* po0   = (__hip_bfloat16*)(ws + (size_t)17825792u);   // 4.19 MB
    __hip_bfloat16* po1   = (__hip_bfloat16*)(ws + (size_t)22020096u);   // 4.19 MB
    __hip_bfloat16* po2   = (__hip_bfloat16*)(ws + (size_t)26214400u);   // 4.19 MB
    __hip_bfloat16* po3   = (__hip_bfloat16*)(ws + (size_t)30408704u);   // 4.19 MB
    float* ls0            = (float*)(ws + (size_t)34603008u);            // 128 KB
    float* ls1            = (float*)(ws + (size_t)34734080u);            // 128 KB
    float* ls2            = (float*)(ws + (size_t)34865152u);            // 128 KB
    float* ls3            = (float*)(ws + (size_t)34996224u);            // 128 KB

    pack_w_kernel<<<128, 256, 0, stream>>>(wq, wk, wv, wo, syn_bias, gid, betaP, wpk);
    qkv_mfma_kernel<<<1536, 256, 0, stream>>>(x, wpk, bq, bk, bv, codons, gid, betaP,
                                              qfrag, kfrag, vfrag);
    attn_kernel<<<1024, 256, 0, stream>>>(qfrag, kfrag, vfrag,
                                          po0, po1, po2, po3, ls0, ls1, ls2, ls3);
    out_proj_kernel<<<512, 256, 0, stream>>>(po0, po1, po2, po3,
                                             ls0, ls1, ls2, ls3, wpk, bo, out);
}

// Round 15
// 80.521 us; speedup vs baseline: 1.1148x; 1.0524x over previous
//
#include <hip/hip_runtime.h>
#include <hip/hip_bf16.h>

#define NH 4
#define HD 64
#define HID 256
#define SS 4096

#define QFRAG_PER_HEAD (128 * 6 * 64 * 8)   // 393216 elems
#define KFRAG_PER_HEAD (64 * 12 * 64 * 8)   // 393216 elems
#define VFRAG_PER_HEAD (64 * 8 * 64 * 8)    // 262144 elems

typedef float f4 __attribute__((ext_vector_type(4)));
typedef float f16v __attribute__((ext_vector_type(16)));
typedef short bf8 __attribute__((ext_vector_type(8)));   // 8 bf16
typedef unsigned int u4v __attribute__((ext_vector_type(4)));

static __device__ __forceinline__ float fast_exp2(float x) {
#if __has_builtin(__builtin_amdgcn_exp2f)
    return __builtin_amdgcn_exp2f(x);
#else
    float r; asm("v_exp_f32 %0, %1" : "=v"(r) : "v"(x)); return r;
#endif
}

static __device__ __forceinline__ unsigned pack2(float a, float b) {
    unsigned ua = (unsigned)__bfloat16_as_ushort(__float2bfloat16(a));
    unsigned ub = (unsigned)__bfloat16_as_ushort(__float2bfloat16(b));
    return ua | (ub << 16);
}

// single-instruction packed f32x2 -> bf16x2 (T12; no builtin on gfx950)
static __device__ __forceinline__ unsigned cvtpk(float a, float b) {
    unsigned r;
    asm("v_cvt_pk_bf16_f32 %0, %1, %2" : "=v"(r) : "v"(a), "v"(b));
    return r;
}

// ---------------------------------------------------------------------------
// Pack wq/wk/wv/wo into MFMA fragment-major bf16. Block 0 additionally
// derives the codon->group-id map + beta*log2e.
// ---------------------------------------------------------------------------
__global__ __launch_bounds__(256)
void pack_w_kernel(const float* __restrict__ wq, const float* __restrict__ wk,
                   const float* __restrict__ wv, const float* __restrict__ wo,
                   const float* __restrict__ syn,
                   int* __restrict__ gid, float* __restrict__ betaP,
                   __hip_bfloat16* __restrict__ wpk)
{
    if (blockIdx.x == 0 && threadIdx.x < 64) {
        const int lane = threadIdx.x;          // 0..63
        int rep = 64;
        for (int j = 63; j >= 0; --j)
            if (syn[lane * 64 + j] != 0.0f) rep = j;
        if (rep == 64) rep = lane;
        unsigned long long m = __ballot(rep == lane);
        int id = (int)__popcll(m & ((2ull << rep) - 1ull)) - 1;
        if (id < 0) id = 0;
        gid[lane] = id;                                 // 0..20
        if (lane == 0) *betaP = syn[0] * 1.44269504088896f;
    }

    const int t = blockIdx.x * 256 + threadIdx.x;   // 0..32767
    const int mat = t >> 13;
    const int r = t & 8191;
    const int dt = r >> 10, ks = (r >> 6) & 15, lane = r & 63;
    const float* w = (mat == 0) ? wq : (mat == 1) ? wk : (mat == 2) ? wv : wo;
    const int row = dt * 32 + (lane & 31);
    const int col = ks * 16 + (lane >> 5) * 8;
    const f4 a = *(const f4*)&w[(size_t)row * 256 + col];
    const f4 b = *(const f4*)&w[(size_t)row * 256 + col + 4];
    union { unsigned u[4]; bf8 v; } o;
    o.u[0] = pack2(a[0], a[1]); o.u[1] = pack2(a[2], a[3]);
    o.u[2] = pack2(b[0], b[1]); o.u[3] = pack2(b[2], b[3]);
    *(bf8*)&wpk[(size_t)t * 8] = o.v;
}

// ---------------------------------------------------------------------------
// QKV projection via MFMA. Grid 768 = 256 stiles x 3 groups; each wave
// computes TWO 32x32 tiles off the same LDS x-tile (x over-read 6x -> 3x;
// qkv was HBM-bound on redundant x reads).
// ---------------------------------------------------------------------------
__global__ __launch_bounds__(256)
void qkv_mfma_kernel(const float* __restrict__ x,
                     const __hip_bfloat16* __restrict__ wpk,
                     const float* __restrict__ bq, const float* __restrict__ bk,
                     const float* __restrict__ bv,
                     const int* __restrict__ codons,
                     const int* __restrict__ gid, const float* __restrict__ betaP,
                     __hip_bfloat16* __restrict__ qfrag,
                     __hip_bfloat16* __restrict__ kfrag,
                     __hip_bfloat16* __restrict__ vfrag)
{
    const int bid = blockIdx.x;
    const int stile = bid / 3;            // 0..255
    const int grp = bid % 3;              // 0..2
    const int tid = threadIdx.x;
    const int w = tid >> 6, lane = tid & 63, hi = lane >> 5, l5 = lane & 31;

    const int bidx = stile >> 7;
    const int stl = stile & 127;
    const int hs = stl & 1, tkv = stl >> 1;

    __shared__ __hip_bfloat16 xs[32][256];

    {
        const int r0 = tid >> 5, c = tid & 31;
        #pragma unroll
        for (int it = 0; it < 4; ++it) {
            const int row = r0 + it * 8;
            const f4 a = *(const f4*)&x[(size_t)(stile * 32 + row) * HID + c * 8];
            const f4 b2 = *(const f4*)&x[(size_t)(stile * 32 + row) * HID + c * 8 + 4];
            union { unsigned u[4]; bf8 v; } o;
            o.u[0] = pack2(a[0], a[1]); o.u[1] = pack2(a[2], a[3]);
            o.u[2] = pack2(b2[0], b2[1]); o.u[3] = pack2(b2[2], b2[3]);
            *(bf8*)&xs[row][((c ^ row) & 31) * 8] = o.v;
        }
    }
    __syncthreads();

    #pragma unroll 1
    for (int hf = 0; hf < 2; ++hf) {
        const int t24 = grp * 8 + hf * 4 + w;   // bijective over 0..23
        const int mat = t24 >> 3;               // 0=q 1=k 2=v
        const int dt = t24 & 7;
        const int head = dt >> 1, d32 = dt & 1;

        const __hip_bfloat16* wb = wpk + (size_t)((mat * 8 + dt) * 16) * 512 + (size_t)lane * 8;
        bf8 wf[16];
        #pragma unroll
        for (int ks = 0; ks < 16; ++ks) wf[ks] = *(const bf8*)&wb[ks * 512];

        f16v acc;
        #pragma unroll
        for (int r = 0; r < 16; ++r) acc[r] = 0.0f;

        if (mat < 2) {
            #pragma unroll
            for (int ks = 0; ks < 16; ++ks) {
                const bf8 xf = *(const bf8*)&xs[l5][(((ks * 2 + hi) ^ l5) & 31) * 8];
                acc = __builtin_amdgcn_mfma_f32_32x32x16_bf16(wf[ks], xf, acc, 0, 0, 0);
            }
        } else {
            #pragma unroll
            for (int ks = 0; ks < 16; ++ks) {
                const bf8 xf = *(const bf8*)&xs[l5][(((ks * 2 + hi) ^ l5) & 31) * 8];
                acc = __builtin_amdgcn_mfma_f32_32x32x16_bf16(xf, wf[ks], acc, 0, 0, 0);
            }
        }

        const float QSCALE = 0.18033688011112042f;   // 0.125 * log2(e)
        if (mat == 0) {
            f4 b4[4];
            #pragma unroll
            for (int j = 0; j < 4; ++j)
                b4[j] = *(const f4*)&bq[head * 64 + d32 * 32 + j * 8 + 4 * hi];
            #pragma unroll
            for (int r = 0; r < 16; ++r) acc[r] = (acc[r] + b4[r >> 2][r & 3]) * QSCALE;
        } else if (mat == 1) {
            f4 b4[4];
            #pragma unroll
            for (int j = 0; j < 4; ++j)
                b4[j] = *(const f4*)&bk[head * 64 + d32 * 32 + j * 8 + 4 * hi];
            #pragma unroll
            for (int r = 0; r < 16; ++r) acc[r] += b4[r >> 2][r & 3];
        } else {
            const float bn = bv[head * 64 + d32 * 32 + l5];
            #pragma unroll
            for (int r = 0; r < 16; ++r) acc[r] += bn;
        }

        unsigned wd[8];
        #pragma unroll
        for (int i = 0; i < 8; ++i) wd[i] = pack2(acc[2 * i], acc[2 * i + 1]);
        const unsigned e0 = (unsigned)__shfl_xor((int)(hi ? wd[0] : wd[2]), 32, 64);
        const unsigned e1 = (unsigned)__shfl_xor((int)(hi ? wd[1] : wd[3]), 32, 64);
        const unsigned e2 = (unsigned)__shfl_xor((int)(hi ? wd[4] : wd[6]), 32, 64);
        const unsigned e3 = (unsigned)__shfl_xor((int)(hi ? wd[5] : wd[7]), 32, 64);
        union { unsigned u[4]; bf8 v; } fa, fb;
        if (hi == 0) {
            fa.u[0] = wd[0]; fa.u[1] = wd[1]; fa.u[2] = e0; fa.u[3] = e1;
            fb.u[0] = wd[4]; fb.u[1] = wd[5]; fb.u[2] = e2; fb.u[3] = e3;
        } else {
            fa.u[0] = e0; fa.u[1] = e1; fa.u[2] = wd[2]; fa.u[3] = wd[3];
            fb.u[0] = e2; fb.u[1] = e3; fb.u[2] = wd[6]; fb.u[3] = wd[7];
        }

        const int hd = bidx * NH + head;
        if (mat == 0) {
            __hip_bfloat16* qb = qfrag + (size_t)hd * QFRAG_PER_HEAD;
            *(bf8*)&qb[((size_t)(stl * 6 + d32 * 2 + 0) * 64 + lane) * 8] = fa.v;
            *(bf8*)&qb[((size_t)(stl * 6 + d32 * 2 + 1) * 64 + lane) * 8] = fb.v;
        } else if (mat == 1) {
            __hip_bfloat16* kb = kfrag + (size_t)hd * KFRAG_PER_HEAD;
            *(bf8*)&kb[((size_t)(tkv * 12 + d32 * 4 + hs) * 64 + lane) * 8] = fa.v;
            *(bf8*)&kb[((size_t)(tkv * 12 + d32 * 4 + 2 + hs) * 64 + lane) * 8] = fb.v;
        } else {
            __hip_bfloat16* vb = vfrag + (size_t)hd * VFRAG_PER_HEAD;
            const int ja = ((stl * 2 + 0) & 3) * 2 + d32;
            const int jb = ((stl * 2 + 1) & 3) * 2 + d32;
            *(bf8*)&vb[((size_t)(tkv * 8 + ja) * 64 + lane) * 8] = fa.v;
            *(bf8*)&vb[((size_t)(tkv * 8 + jb) * 64 + lane) * 8] = fb.v;
        }
    }

    // ---- augmentation dims (grp 0 blocks: wave w -> head w)
    if (grp == 0) {
        const int hh = w;
        const int hd2 = bidx * NH + hh;
        __hip_bfloat16* qb = qfrag + (size_t)hd2 * QFRAG_PER_HEAD;
        __hip_bfloat16* kb = kfrag + (size_t)hd2 * KFRAG_PER_HEAD;
        u4v z; z[0] = 0; z[1] = 0; z[2] = 0; z[3] = 0;
        *(u4v*)&qb[((size_t)(stl * 6 + 4) * 64 + lane) * 8] = z;
        *(u4v*)&qb[((size_t)(stl * 6 + 5) * 64 + lane) * 8] = z;
        *(u4v*)&kb[((size_t)(tkv * 12 + 8 + hs) * 64 + lane) * 8] = z;
        *(u4v*)&kb[((size_t)(tkv * 12 + 10 + hs) * 64 + lane) * 8] = z;
        asm volatile("s_waitcnt vmcnt(0)" ::: "memory");
        if (hi == 0) {
            const int cg = gid[codons[bidx * SS + stl * 32 + l5] & 63];
            const float bl2e = *betaP;
            const int lt = ((cg >> 3) & 1) * 32 + l5;
            qb[((size_t)(stl * 6 + 4 + (cg >> 4)) * 64 + lt) * 8 + (cg & 7)] =
                __float2bfloat16(bl2e);
            kb[((size_t)(tkv * 12 + 8 + (cg >> 4) * 2 + hs) * 64 + lt) * 8 + (cg & 7)] =
                __float2bfloat16(1.0f);
        }
    }
}

// ---------------------------------------------------------------------------
// Flash attention (R14, unchanged): global_load_lds staging, no setprio,
// cvt_pk + permlane32_swap pack-exchange. Grid 1024 KV-quarters.
// ---------------------------------------------------------------------------
__global__ __launch_bounds__(256, 4)
void attn_kernel(const __hip_bfloat16* __restrict__ qfrag,
                 const __hip_bfloat16* __restrict__ kfrag,
                 const __hip_bfloat16* __restrict__ vfrag,
                 __hip_bfloat16* __restrict__ po0,
                 __hip_bfloat16* __restrict__ po1,
                 __hip_bfloat16* __restrict__ po2,
                 __hip_bfloat16* __restrict__ po3,
                 float* __restrict__ ls0, float* __restrict__ ls1,
                 float* __restrict__ ls2, float* __restrict__ ls3)
{
    const int bid = blockIdx.x;           // 1024 blocks
    const int bh = bid & 7;               // XCD-pinned (b,h)
    const int b = bh >> 2, h = bh & 3;
    const int quarter = (bid >> 3) & 3;
    const int qg = bid >> 5;              // 0..31 -> rows [qg*128, +128)
    const int tid = threadIdx.x;
    const int w = tid >> 6;               // wave -> 32-row q-subtile
    const int lane = tid & 63;
    const int q5 = lane & 31;
    const int hi = lane >> 5;

    __shared__ __align__(16) char smem[40960];   // 2 x 20KB KV tile; epilogue overlay

    const char* kT = (const char*)(kfrag + (size_t)(b * NH + h) * KFRAG_PER_HEAD);
    const char* vT = (const char*)(vfrag + (size_t)(b * NH + h) * VFRAG_PER_HEAD);

    // ---- Q fragments: wave w owns stile qg*4+w
    const int stl = qg * 4 + w;
    const __hip_bfloat16* qb = qfrag + (size_t)(b * NH + h) * QFRAG_PER_HEAD
                               + ((size_t)stl * 6 * 64 + lane) * 8;
    bf8 qf[6];
    #pragma unroll
    for (int ks = 0; ks < 6; ++ks) qf[ks] = *(const bf8*)&qb[ks * 512];

    f16v oacc0, oacc1;
    #pragma unroll
    for (int r = 0; r < 16; ++r) { oacc0[r] = 0.0f; oacc1[r] = 0.0f; }
    float lrun = 0.0f;

    const int w5 = w * 5;                 // this wave stages chunks w5..w5+4 (of 20)
    const int tt0 = quarter * 16;

    auto stage = [&](int buf, int t) {
        const int tt = tt0 + t;
        #pragma unroll
        for (int c = 0; c < 5; ++c) {
            const int id = w5 + c;
            const char* src = (id < 12)
                ? kT + (size_t)tt * 12288 + (size_t)id * 1024
                : vT + (size_t)tt * 8192 + (size_t)(id - 12) * 1024;
            __builtin_amdgcn_global_load_lds(
                (const __attribute__((address_space(1))) unsigned int*)(src + lane * 16),
                (__attribute__((address_space(3))) unsigned int*)(smem + buf * 20480 + id * 1024),
                16, 0, 0);
        }
    };

    stage(0, 0);
    __syncthreads();

    int cur = 0;
    #pragma unroll 1
    for (int t = 0; t < 16; ++t) {
        if (t + 1 < 16) stage(cur ^ 1, t + 1);   // in-flight under compute

        const char* kb = smem + cur * 20480 + lane * 16;

        // ---- QK^T (swapped): D[key][q]
        f16v sA, sB;
        #pragma unroll
        for (int r = 0; r < 16; ++r) { sA[r] = 0.0f; sB[r] = 0.0f; }
        #pragma unroll
        for (int ks = 0; ks < 6; ++ks) {
            const bf8 k0 = *(const bf8*)(kb + (2 * ks) * 1024);
            const bf8 k1 = *(const bf8*)(kb + (2 * ks + 1) * 1024);
            sA = __builtin_amdgcn_mfma_f32_32x32x16_bf16(k0, qf[ks], sA, 0, 0, 0);
            sB = __builtin_amdgcn_mfma_f32_32x32x16_bf16(k1, qf[ks], sB, 0, 0, 0);
        }

        // ---- p = 2^s
        float ls = 0.0f;
        #pragma unroll
        for (int r = 0; r < 16; ++r) { sA[r] = fast_exp2(sA[r]); ls += sA[r]; }
        #pragma unroll
        for (int r = 0; r < 16; ++r) { sB[r] = fast_exp2(sB[r]); ls += sB[r]; }
        lrun += ls;

        // ---- cvt_pk + permlane32_swap pack-exchange -> PV B fragments
        bf8 pfv[4];
        #pragma unroll
        for (int t2 = 0; t2 < 2; ++t2) {
            const f16v& s = t2 ? sB : sA;
            unsigned dwv[4][2];
            #pragma unroll
            for (int j = 0; j < 4; ++j)
                #pragma unroll
                for (int c = 0; c < 2; ++c)
                    dwv[j][c] = cvtpk(s[j * 4 + 2 * c], s[j * 4 + 2 * c + 1]);
            #pragma unroll
            for (int k1 = 0; k1 < 2; ++k1) {
                union { unsigned u[4]; bf8 v; } pu;
                #pragma unroll
                for (int c = 0; c < 2; ++c) {
                    unsigned a = dwv[2 * k1][c];
                    unsigned bch = dwv[2 * k1 + 1][c];
                    asm volatile("v_permlane32_swap_b32 %0, %1"
                                 : "+v"(a), "+v"(bch));
                    pu.u[c] = a;
                    pu.u[2 + c] = bch;
                }
                pfv[t2 * 2 + k1] = pu.v;
            }
        }

        // ---- PV
        #pragma unroll
        for (int ks = 0; ks < 4; ++ks) {
            const bf8 v0 = *(const bf8*)(kb + (12 + 2 * ks) * 1024);
            const bf8 v1 = *(const bf8*)(kb + (13 + 2 * ks) * 1024);
            oacc0 = __builtin_amdgcn_mfma_f32_32x32x16_bf16(v0, pfv[ks], oacc0, 0, 0, 0);
            oacc1 = __builtin_amdgcn_mfma_f32_32x32x16_bf16(v1, pfv[ks], oacc1, 0, 0, 0);
        }

        __syncthreads();                   // drains stage(t+1) DMA; swap buffers
        cur ^= 1;
    }

    // ---- epilogue: partials -> LDS overlay (pitch 66) -> coalesced bf16 dump
    const float ltot = lrun + __shfl_xor(lrun, 32, 64);
    float* osh = (float*)smem;                 // 128 rows x 66 floats = 33792 B
    float* lsh = (float*)(smem + 33792);       // 128 floats
    #pragma unroll
    for (int r = 0; r < 16; ++r) {
        const int d = (r & 3) + 8 * (r >> 2) + 4 * hi;
        osh[(w * 32 + q5) * 66 + d] = oacc0[r];
        osh[(w * 32 + q5) * 66 + 32 + d] = oacc1[r];
    }
    if (hi == 0) lsh[w * 32 + q5] = ltot;
    __syncthreads();

    __hip_bfloat16* pob = (quarter == 0) ? po0 : (quarter == 1) ? po1
                        : (quarter == 2) ? po2 : po3;
    float* lsb = (quarter == 0) ? ls0 : (quarter == 1) ? ls1
               : (quarter == 2) ? ls2 : ls3;
    const int row = tid >> 1;
    const int dh = (tid & 1) * 32;
    const float* src = &osh[row * 66 + dh];
    __hip_bfloat16* dst = pob + ((size_t)(b * SS + qg * 128 + row) * HID + h * HD + dh);
    #pragma unroll
    for (int j = 0; j < 4; ++j) {
        const f4 x0 = *(const f4*)&src[j * 8];
        const f4 x1 = *(const f4*)&src[j * 8 + 4];
        union { unsigned u[4]; bf8 v; } o;
        o.u[0] = pack2(x0[0], x0[1]); o.u[1] = pack2(x0[2], x0[3]);
        o.u[2] = pack2(x1[0], x1[1]); o.u[3] = pack2(x1[2], x1[3]);
        *(bf8*)&dst[j * 8] = o.v;
    }
    if (tid < 128) lsb[(size_t)(b * SS + qg * 128 + tid) * 4 + h] = lsh[tid];
}

// ---------------------------------------------------------------------------
// Output projection via MFMA; merges the four KV-quarter partials in staging.
// ---------------------------------------------------------------------------
__global__ __launch_bounds__(256)
void out_proj_kernel(const __hip_bfloat16* __restrict__ po0,
                     const __hip_bfloat16* __restrict__ po1,
                     const __hip_bfloat16* __restrict__ po2,
                     const __hip_bfloat16* __restrict__ po3,
                     const float* __restrict__ ls0, const float* __restrict__ ls1,
                     const float* __restrict__ ls2, const float* __restrict__ ls3,
                     const __hip_bfloat16* __restrict__ wpk,
                     const float* __restrict__ bo, float* __restrict__ out)
{
    const int bid = blockIdx.x;
    const int stile = bid >> 1, grp = bid & 1;
    const int tid = threadIdx.x;
    const int w = tid >> 6, lane = tid & 63, hi = lane >> 5, l5 = lane & 31;

    __shared__ __hip_bfloat16 xs[32][256];
    {
        const int r0 = tid >> 5, c = tid & 31;
        #pragma unroll
        for (int it = 0; it < 4; ++it) {
            const int row = r0 + it * 8;
            const size_t srow = (size_t)stile * 32 + row;
            const int head = c >> 3;
            const float inv = 1.0f / (ls0[srow * 4 + head] + ls1[srow * 4 + head]
                                    + ls2[srow * 4 + head] + ls3[srow * 4 + head]);
            union { bf8 v; unsigned u[4]; } a0, a1, a2, a3;
            a0.v = *(const bf8*)&po0[srow * 256 + c * 8];
            a1.v = *(const bf8*)&po1[srow * 256 + c * 8];
            a2.v = *(const bf8*)&po2[srow * 256 + c * 8];
            a3.v = *(const bf8*)&po3[srow * 256 + c * 8];
            union { unsigned u[4]; bf8 v; } o;
            #pragma unroll
            for (int i = 0; i < 4; ++i) {
                const float lo = __uint_as_float(a0.u[i] << 16)
                               + __uint_as_float(a1.u[i] << 16)
                               + __uint_as_float(a2.u[i] << 16)
                               + __uint_as_float(a3.u[i] << 16);
                const float hv = __uint_as_float(a0.u[i] & 0xffff0000u)
                               + __uint_as_float(a1.u[i] & 0xffff0000u)
                               + __uint_as_float(a2.u[i] & 0xffff0000u)
                               + __uint_as_float(a3.u[i] & 0xffff0000u);
                o.u[i] = pack2(lo * inv, hv * inv);
            }
            *(bf8*)&xs[row][((c ^ row) & 31) * 8] = o.v;
        }
    }
    __syncthreads();

    const int nt = grp * 4 + w;           // 0..7
    const __hip_bfloat16* wb = wpk + (size_t)((3 * 8 + nt) * 16) * 512 + (size_t)lane * 8;
    bf8 wf[16];
    #pragma unroll
    for (int ks = 0; ks < 16; ++ks) wf[ks] = *(const bf8*)&wb[ks * 512];

    f16v acc;
    #pragma unroll
    for (int r = 0; r < 16; ++r) acc[r] = 0.0f;
    #pragma unroll
    for (int ks = 0; ks < 16; ++ks) {
        const bf8 xf = *(const bf8*)&xs[l5][(((ks * 2 + hi) ^ l5) & 31) * 8];
        acc = __builtin_amdgcn_mfma_f32_32x32x16_bf16(xf, wf[ks], acc, 0, 0, 0);
    }

    const float bn = bo[nt * 32 + l5];
    #pragma unroll
    for (int r = 0; r < 16; ++r) {
        const int sloc = (r & 3) + 8 * (r >> 2) + 4 * hi;
        out[(size_t)(stile * 32 + sloc) * HID + nt * 32 + l5] = acc[r] + bn;
    }
}

extern "C" void kernel_launch(void* const* d_in, const int* in_sizes, int n_in,
                              void* d_out, int out_size, void* d_ws, size_t ws_size,
                              hipStream_t stream)
{
    (void)in_sizes; (void)n_in; (void)out_size; (void)ws_size;
    const float* x        = (const float*)d_in[0];
    const int*   codons   = (const int*)d_in[1];
    const float* syn_bias = (const float*)d_in[2];
    const float* wq = (const float*)d_in[3];
    const float* bq = (const float*)d_in[4];
    const float* wk = (const float*)d_in[5];
    const float* bk = (const float*)d_in[6];
    const float* wv = (const float*)d_in[7];
    const float* bv = (const float*)d_in[8];
    const float* wo = (const float*)d_in[9];
    const float* bo = (const float*)d_in[10];
    float* out = (float*)d_out;

    char* ws = (char*)d_ws;
    int*   gid   = (int*)(ws);                                  // 256 B
    float* betaP = (float*)(ws + 256);                          // 4 B
    __hip_bfloat16* wpk   = (__hip_bfloat16*)(ws + 4096);       // 512 KB
    __hip_bfloat16* qfrag = (__hip_bfloat16*)(ws + (size_t)1048576u);    // 6.29 MB
    __hip_bfloat16* kfrag = (__hip_bfloat16*)(ws + (size_t)7340032u);    // 6.29 MB
    __hip_bfloat16* vfrag = (__hip_bfloat16*)(ws + (size_t)13631488u);   // 4.19 MB
    __hip_bfloat16* po0   = (__hip_bfloat16*)(ws + (size_t)17825792u);   // 4.19 MB
    __hip_bfloat16* po1   = (__hip_bfloat16*)(ws + (size_t)22020096u);   // 4.19 MB
    __hip_bfloat16* po2   = (__hip_bfloat16*)(ws + (size_t)26214400u);   // 4.19 MB
    __hip_bfloat16* po3   = (__hip_bfloat16*)(ws + (size_t)30408704u);   // 4.19 MB
    float* ls0            = (float*)(ws + (size_t)34603008u);            // 128 KB
    float* ls1            = (float*)(ws + (size_t)34734080u);            // 128 KB
    float* ls2            = (float*)(ws + (size_t)34865152u);            // 128 KB
    float* ls3            = (float*)(ws + (size_t)34996224u);            // 128 KB

    pack_w_kernel<<<128, 256, 0, stream>>>(wq, wk, wv, wo, syn_bias, gid, betaP, wpk);
    qkv_mfma_kernel<<<768, 256, 0, stream>>>(x, wpk, bq, bk, bv, codons, gid, betaP,
                                             qfrag, kfrag, vfrag);
    attn_kernel<<<1024, 256, 0, stream>>>(qfrag, kfrag, vfrag,
                                          po0, po1, po2, po3, ls0, ls1, ls2, ls3);
    out_proj_kernel<<<512, 256, 0, stream>>>(po0, po1, po2, po3,
                                             ls0, ls1, ls2, ls3, wpk, bo, out);
}

// Round 16
// 80.373 us; speedup vs baseline: 1.1169x; 1.0018x over previous
//
#include <hip/hip_runtime.h>
#include <hip/hip_bf16.h>

#define NH 4
#define HD 64
#define HID 256
#define SS 4096

#define QFRAG_PER_HEAD (128 * 6 * 64 * 8)   // 393216 elems
#define KFRAG_PER_HEAD (64 * 12 * 64 * 8)   // 393216 elems
#define VFRAG_PER_HEAD (64 * 8 * 64 * 8)    // 262144 elems

typedef float f4 __attribute__((ext_vector_type(4)));
typedef float f16v __attribute__((ext_vector_type(16)));
typedef short bf8 __attribute__((ext_vector_type(8)));   // 8 bf16
typedef unsigned int u4v __attribute__((ext_vector_type(4)));

static __device__ __forceinline__ float fast_exp2(float x) {
#if __has_builtin(__builtin_amdgcn_exp2f)
    return __builtin_amdgcn_exp2f(x);
#else
    float r; asm("v_exp_f32 %0, %1" : "=v"(r) : "v"(x)); return r;
#endif
}

static __device__ __forceinline__ unsigned pack2(float a, float b) {
    unsigned ua = (unsigned)__bfloat16_as_ushort(__float2bfloat16(a));
    unsigned ub = (unsigned)__bfloat16_as_ushort(__float2bfloat16(b));
    return ua | (ub << 16);
}

// single-instruction packed f32x2 -> bf16x2 (T12; no builtin on gfx950)
static __device__ __forceinline__ unsigned cvtpk(float a, float b) {
    unsigned r;
    asm("v_cvt_pk_bf16_f32 %0, %1, %2" : "=v"(r) : "v"(a), "v"(b));
    return r;
}

// ---------------------------------------------------------------------------
// Pack wq/wk/wv/wo into MFMA fragment-major bf16. Block 0 additionally
// derives the codon->group-id map + beta*log2e.
// ---------------------------------------------------------------------------
__global__ __launch_bounds__(256)
void pack_w_kernel(const float* __restrict__ wq, const float* __restrict__ wk,
                   const float* __restrict__ wv, const float* __restrict__ wo,
                   const float* __restrict__ syn,
                   int* __restrict__ gid, float* __restrict__ betaP,
                   __hip_bfloat16* __restrict__ wpk)
{
    if (blockIdx.x == 0 && threadIdx.x < 64) {
        const int lane = threadIdx.x;          // 0..63
        int rep = 64;
        for (int j = 63; j >= 0; --j)
            if (syn[lane * 64 + j] != 0.0f) rep = j;
        if (rep == 64) rep = lane;
        unsigned long long m = __ballot(rep == lane);
        int id = (int)__popcll(m & ((2ull << rep) - 1ull)) - 1;
        if (id < 0) id = 0;
        gid[lane] = id;                                 // 0..20
        if (lane == 0) *betaP = syn[0] * 1.44269504088896f;
    }

    const int t = blockIdx.x * 256 + threadIdx.x;   // 0..32767
    const int mat = t >> 13;
    const int r = t & 8191;
    const int dt = r >> 10, ks = (r >> 6) & 15, lane = r & 63;
    const float* w = (mat == 0) ? wq : (mat == 1) ? wk : (mat == 2) ? wv : wo;
    const int row = dt * 32 + (lane & 31);
    const int col = ks * 16 + (lane >> 5) * 8;
    const f4 a = *(const f4*)&w[(size_t)row * 256 + col];
    const f4 b = *(const f4*)&w[(size_t)row * 256 + col + 4];
    union { unsigned u[4]; bf8 v; } o;
    o.u[0] = pack2(a[0], a[1]); o.u[1] = pack2(a[2], a[3]);
    o.u[2] = pack2(b[0], b[1]); o.u[3] = pack2(b[2], b[3]);
    *(bf8*)&wpk[(size_t)t * 8] = o.v;
}

// ---------------------------------------------------------------------------
// QKV projection via MFMA. Grid 768 = 256 stiles x 3 groups; each wave
// computes TWO 32x32 tiles off the same LDS x-tile.
// ---------------------------------------------------------------------------
__global__ __launch_bounds__(256)
void qkv_mfma_kernel(const float* __restrict__ x,
                     const __hip_bfloat16* __restrict__ wpk,
                     const float* __restrict__ bq, const float* __restrict__ bk,
                     const float* __restrict__ bv,
                     const int* __restrict__ codons,
                     const int* __restrict__ gid, const float* __restrict__ betaP,
                     __hip_bfloat16* __restrict__ qfrag,
                     __hip_bfloat16* __restrict__ kfrag,
                     __hip_bfloat16* __restrict__ vfrag)
{
    const int bid = blockIdx.x;
    const int stile = bid / 3;            // 0..255
    const int grp = bid % 3;              // 0..2
    const int tid = threadIdx.x;
    const int w = tid >> 6, lane = tid & 63, hi = lane >> 5, l5 = lane & 31;

    const int bidx = stile >> 7;
    const int stl = stile & 127;
    const int hs = stl & 1, tkv = stl >> 1;

    __shared__ __hip_bfloat16 xs[32][256];

    {
        const int r0 = tid >> 5, c = tid & 31;
        #pragma unroll
        for (int it = 0; it < 4; ++it) {
            const int row = r0 + it * 8;
            const f4 a = *(const f4*)&x[(size_t)(stile * 32 + row) * HID + c * 8];
            const f4 b2 = *(const f4*)&x[(size_t)(stile * 32 + row) * HID + c * 8 + 4];
            union { unsigned u[4]; bf8 v; } o;
            o.u[0] = pack2(a[0], a[1]); o.u[1] = pack2(a[2], a[3]);
            o.u[2] = pack2(b2[0], b2[1]); o.u[3] = pack2(b2[2], b2[3]);
            *(bf8*)&xs[row][((c ^ row) & 31) * 8] = o.v;
        }
    }
    __syncthreads();

    #pragma unroll 1
    for (int hf = 0; hf < 2; ++hf) {
        const int t24 = grp * 8 + hf * 4 + w;   // bijective over 0..23
        const int mat = t24 >> 3;               // 0=q 1=k 2=v
        const int dt = t24 & 7;
        const int head = dt >> 1, d32 = dt & 1;

        const __hip_bfloat16* wb = wpk + (size_t)((mat * 8 + dt) * 16) * 512 + (size_t)lane * 8;
        bf8 wf[16];
        #pragma unroll
        for (int ks = 0; ks < 16; ++ks) wf[ks] = *(const bf8*)&wb[ks * 512];

        f16v acc;
        #pragma unroll
        for (int r = 0; r < 16; ++r) acc[r] = 0.0f;

        if (mat < 2) {
            #pragma unroll
            for (int ks = 0; ks < 16; ++ks) {
                const bf8 xf = *(const bf8*)&xs[l5][(((ks * 2 + hi) ^ l5) & 31) * 8];
                acc = __builtin_amdgcn_mfma_f32_32x32x16_bf16(wf[ks], xf, acc, 0, 0, 0);
            }
        } else {
            #pragma unroll
            for (int ks = 0; ks < 16; ++ks) {
                const bf8 xf = *(const bf8*)&xs[l5][(((ks * 2 + hi) ^ l5) & 31) * 8];
                acc = __builtin_amdgcn_mfma_f32_32x32x16_bf16(xf, wf[ks], acc, 0, 0, 0);
            }
        }

        const float QSCALE = 0.18033688011112042f;   // 0.125 * log2(e)
        if (mat == 0) {
            f4 b4[4];
            #pragma unroll
            for (int j = 0; j < 4; ++j)
                b4[j] = *(const f4*)&bq[head * 64 + d32 * 32 + j * 8 + 4 * hi];
            #pragma unroll
            for (int r = 0; r < 16; ++r) acc[r] = (acc[r] + b4[r >> 2][r & 3]) * QSCALE;
        } else if (mat == 1) {
            f4 b4[4];
            #pragma unroll
            for (int j = 0; j < 4; ++j)
                b4[j] = *(const f4*)&bk[head * 64 + d32 * 32 + j * 8 + 4 * hi];
            #pragma unroll
            for (int r = 0; r < 16; ++r) acc[r] += b4[r >> 2][r & 3];
        } else {
            const float bn = bv[head * 64 + d32 * 32 + l5];
            #pragma unroll
            for (int r = 0; r < 16; ++r) acc[r] += bn;
        }

        unsigned wd[8];
        #pragma unroll
        for (int i = 0; i < 8; ++i) wd[i] = pack2(acc[2 * i], acc[2 * i + 1]);
        const unsigned e0 = (unsigned)__shfl_xor((int)(hi ? wd[0] : wd[2]), 32, 64);
        const unsigned e1 = (unsigned)__shfl_xor((int)(hi ? wd[1] : wd[3]), 32, 64);
        const unsigned e2 = (unsigned)__shfl_xor((int)(hi ? wd[4] : wd[6]), 32, 64);
        const unsigned e3 = (unsigned)__shfl_xor((int)(hi ? wd[5] : wd[7]), 32, 64);
        union { unsigned u[4]; bf8 v; } fa, fb;
        if (hi == 0) {
            fa.u[0] = wd[0]; fa.u[1] = wd[1]; fa.u[2] = e0; fa.u[3] = e1;
            fb.u[0] = wd[4]; fb.u[1] = wd[5]; fb.u[2] = e2; fb.u[3] = e3;
        } else {
            fa.u[0] = e0; fa.u[1] = e1; fa.u[2] = wd[2]; fa.u[3] = wd[3];
            fb.u[0] = e2; fb.u[1] = e3; fb.u[2] = wd[6]; fb.u[3] = wd[7];
        }

        const int hd = bidx * NH + head;
        if (mat == 0) {
            __hip_bfloat16* qb = qfrag + (size_t)hd * QFRAG_PER_HEAD;
            *(bf8*)&qb[((size_t)(stl * 6 + d32 * 2 + 0) * 64 + lane) * 8] = fa.v;
            *(bf8*)&qb[((size_t)(stl * 6 + d32 * 2 + 1) * 64 + lane) * 8] = fb.v;
        } else if (mat == 1) {
            __hip_bfloat16* kb = kfrag + (size_t)hd * KFRAG_PER_HEAD;
            *(bf8*)&kb[((size_t)(tkv * 12 + d32 * 4 + hs) * 64 + lane) * 8] = fa.v;
            *(bf8*)&kb[((size_t)(tkv * 12 + d32 * 4 + 2 + hs) * 64 + lane) * 8] = fb.v;
        } else {
            __hip_bfloat16* vb = vfrag + (size_t)hd * VFRAG_PER_HEAD;
            const int ja = ((stl * 2 + 0) & 3) * 2 + d32;
            const int jb = ((stl * 2 + 1) & 3) * 2 + d32;
            *(bf8*)&vb[((size_t)(tkv * 8 + ja) * 64 + lane) * 8] = fa.v;
            *(bf8*)&vb[((size_t)(tkv * 8 + jb) * 64 + lane) * 8] = fb.v;
        }
    }

    // ---- augmentation dims (grp 0 blocks: wave w -> head w)
    if (grp == 0) {
        const int hh = w;
        const int hd2 = bidx * NH + hh;
        __hip_bfloat16* qb = qfrag + (size_t)hd2 * QFRAG_PER_HEAD;
        __hip_bfloat16* kb = kfrag + (size_t)hd2 * KFRAG_PER_HEAD;
        u4v z; z[0] = 0; z[1] = 0; z[2] = 0; z[3] = 0;
        *(u4v*)&qb[((size_t)(stl * 6 + 4) * 64 + lane) * 8] = z;
        *(u4v*)&qb[((size_t)(stl * 6 + 5) * 64 + lane) * 8] = z;
        *(u4v*)&kb[((size_t)(tkv * 12 + 8 + hs) * 64 + lane) * 8] = z;
        *(u4v*)&kb[((size_t)(tkv * 12 + 10 + hs) * 64 + lane) * 8] = z;
        asm volatile("s_waitcnt vmcnt(0)" ::: "memory");
        if (hi == 0) {
            const int cg = gid[codons[bidx * SS + stl * 32 + l5] & 63];
            const float bl2e = *betaP;
            const int lt = ((cg >> 3) & 1) * 32 + l5;
            qb[((size_t)(stl * 6 + 4 + (cg >> 4)) * 64 + lt) * 8 + (cg & 7)] =
                __float2bfloat16(bl2e);
            kb[((size_t)(tkv * 12 + 8 + (cg >> 4) * 2 + hs) * 64 + lt) * 8 + (cg & 7)] =
                __float2bfloat16(1.0f);
        }
    }
}

// ---------------------------------------------------------------------------
// Flash attention: R14/R15 structure + T3/T4 counted-vmcnt pipeline:
// 3-buffer LDS rotation, stage(t+2) issued at iter top, s_waitcnt vmcnt(5)
// (never 0 mid-loop) + raw s_barrier — next tile's DMA stays in flight
// ACROSS the barrier (removes the vmcnt(0) drain stall).
// ---------------------------------------------------------------------------
__global__ __launch_bounds__(256, 2)
void attn_kernel(const __hip_bfloat16* __restrict__ qfrag,
                 const __hip_bfloat16* __restrict__ kfrag,
                 const __hip_bfloat16* __restrict__ vfrag,
                 __hip_bfloat16* __restrict__ po0,
                 __hip_bfloat16* __restrict__ po1,
                 __hip_bfloat16* __restrict__ po2,
                 __hip_bfloat16* __restrict__ po3,
                 float* __restrict__ ls0, float* __restrict__ ls1,
                 float* __restrict__ ls2, float* __restrict__ ls3)
{
    const int bid = blockIdx.x;           // 1024 blocks
    const int bh = bid & 7;               // XCD-pinned (b,h)
    const int b = bh >> 2, h = bh & 3;
    const int quarter = (bid >> 3) & 3;
    const int qg = bid >> 5;              // 0..31 -> rows [qg*128, +128)
    const int tid = threadIdx.x;
    const int w = tid >> 6;               // wave -> 32-row q-subtile
    const int lane = tid & 63;
    const int q5 = lane & 31;
    const int hi = lane >> 5;

    __shared__ __align__(16) char smem[61440];   // 3 x 20KB KV tile; epilogue overlay

    const char* kT = (const char*)(kfrag + (size_t)(b * NH + h) * KFRAG_PER_HEAD);
    const char* vT = (const char*)(vfrag + (size_t)(b * NH + h) * VFRAG_PER_HEAD);

    // ---- Q fragments: wave w owns stile qg*4+w
    const int stl = qg * 4 + w;
    const __hip_bfloat16* qb = qfrag + (size_t)(b * NH + h) * QFRAG_PER_HEAD
                               + ((size_t)stl * 6 * 64 + lane) * 8;
    bf8 qf[6];
    #pragma unroll
    for (int ks = 0; ks < 6; ++ks) qf[ks] = *(const bf8*)&qb[ks * 512];

    f16v oacc0, oacc1;
    #pragma unroll
    for (int r = 0; r < 16; ++r) { oacc0[r] = 0.0f; oacc1[r] = 0.0f; }
    float lrun = 0.0f;

    const int w5 = w * 5;                 // this wave stages chunks w5..w5+4 (of 20)
    const int tt0 = quarter * 16;

    auto stage = [&](int buf, int t) {
        const int tt = tt0 + t;
        #pragma unroll
        for (int c = 0; c < 5; ++c) {
            const int id = w5 + c;
            const char* src = (id < 12)
                ? kT + (size_t)tt * 12288 + (size_t)id * 1024
                : vT + (size_t)tt * 8192 + (size_t)(id - 12) * 1024;
            __builtin_amdgcn_global_load_lds(
                (const __attribute__((address_space(1))) unsigned int*)(src + lane * 16),
                (__attribute__((address_space(3))) unsigned int*)(smem + buf * 20480 + id * 1024),
                16, 0, 0);
        }
    };

    // prologue: tiles 0,1 in flight; wait tile0 only (tile1 flies across barrier)
    stage(0, 0);
    stage(1, 1);
    asm volatile("s_waitcnt vmcnt(5)" ::: "memory");
    __builtin_amdgcn_sched_barrier(0);
    __builtin_amdgcn_s_barrier();

    int bT = 0, bT1 = 1, bT2 = 2;
    #pragma unroll 1
    for (int t = 0; t < 16; ++t) {
        if (t + 2 < 16) stage(bT2, t + 2);   // deepen pipeline (10 loads in flight)

        const char* kb = smem + bT * 20480 + lane * 16;

        // ---- QK^T (swapped): D[key][q]
        f16v sA, sB;
        #pragma unroll
        for (int r = 0; r < 16; ++r) { sA[r] = 0.0f; sB[r] = 0.0f; }
        #pragma unroll
        for (int ks = 0; ks < 6; ++ks) {
            const bf8 k0 = *(const bf8*)(kb + (2 * ks) * 1024);
            const bf8 k1 = *(const bf8*)(kb + (2 * ks + 1) * 1024);
            sA = __builtin_amdgcn_mfma_f32_32x32x16_bf16(k0, qf[ks], sA, 0, 0, 0);
            sB = __builtin_amdgcn_mfma_f32_32x32x16_bf16(k1, qf[ks], sB, 0, 0, 0);
        }

        // ---- p = 2^s
        float ls = 0.0f;
        #pragma unroll
        for (int r = 0; r < 16; ++r) { sA[r] = fast_exp2(sA[r]); ls += sA[r]; }
        #pragma unroll
        for (int r = 0; r < 16; ++r) { sB[r] = fast_exp2(sB[r]); ls += sB[r]; }
        lrun += ls;

        // ---- cvt_pk + permlane32_swap pack-exchange -> PV B fragments
        bf8 pfv[4];
        #pragma unroll
        for (int t2 = 0; t2 < 2; ++t2) {
            const f16v& s = t2 ? sB : sA;
            unsigned dwv[4][2];
            #pragma unroll
            for (int j = 0; j < 4; ++j)
                #pragma unroll
                for (int c = 0; c < 2; ++c)
                    dwv[j][c] = cvtpk(s[j * 4 + 2 * c], s[j * 4 + 2 * c + 1]);
            #pragma unroll
            for (int k1 = 0; k1 < 2; ++k1) {
                union { unsigned u[4]; bf8 v; } pu;
                #pragma unroll
                for (int c = 0; c < 2; ++c) {
                    unsigned a = dwv[2 * k1][c];
                    unsigned bch = dwv[2 * k1 + 1][c];
                    asm volatile("v_permlane32_swap_b32 %0, %1"
                                 : "+v"(a), "+v"(bch));
                    pu.u[c] = a;
                    pu.u[2 + c] = bch;
                }
                pfv[t2 * 2 + k1] = pu.v;
            }
        }

        // ---- PV
        #pragma unroll
        for (int ks = 0; ks < 4; ++ks) {
            const bf8 v0 = *(const bf8*)(kb + (12 + 2 * ks) * 1024);
            const bf8 v1 = *(const bf8*)(kb + (13 + 2 * ks) * 1024);
            oacc0 = __builtin_amdgcn_mfma_f32_32x32x16_bf16(v0, pfv[ks], oacc0, 0, 0, 0);
            oacc1 = __builtin_amdgcn_mfma_f32_32x32x16_bf16(v1, pfv[ks], oacc1, 0, 0, 0);
        }

        // ---- counted drain: wait for tile t+1 ONLY (t+2 stays in flight)
        if (t + 2 < 16) {
            asm volatile("s_waitcnt vmcnt(5)" ::: "memory");
        } else if (t + 1 < 16) {
            asm volatile("s_waitcnt vmcnt(0)" ::: "memory");
        }
        __builtin_amdgcn_sched_barrier(0);
        __builtin_amdgcn_s_barrier();

        const int tmp = bT; bT = bT1; bT1 = bT2; bT2 = tmp;
    }

    // ---- epilogue: partials -> LDS overlay (pitch 66) -> coalesced bf16 dump
    const float ltot = lrun + __shfl_xor(lrun, 32, 64);
    float* osh = (float*)smem;                 // 128 rows x 66 floats = 33792 B
    float* lsh = (float*)(smem + 33792);       // 128 floats
    #pragma unroll
    for (int r = 0; r < 16; ++r) {
        const int d = (r & 3) + 8 * (r >> 2) + 4 * hi;
        osh[(w * 32 + q5) * 66 + d] = oacc0[r];
        osh[(w * 32 + q5) * 66 + 32 + d] = oacc1[r];
    }
    if (hi == 0) lsh[w * 32 + q5] = ltot;
    __syncthreads();

    __hip_bfloat16* pob = (quarter == 0) ? po0 : (quarter == 1) ? po1
                        : (quarter == 2) ? po2 : po3;
    float* lsb = (quarter == 0) ? ls0 : (quarter == 1) ? ls1
               : (quarter == 2) ? ls2 : ls3;
    const int row = tid >> 1;
    const int dh = (tid & 1) * 32;
    const float* src = &osh[row * 66 + dh];
    __hip_bfloat16* dst = pob + ((size_t)(b * SS + qg * 128 + row) * HID + h * HD + dh);
    #pragma unroll
    for (int j = 0; j < 4; ++j) {
        const f4 x0 = *(const f4*)&src[j * 8];
        const f4 x1 = *(const f4*)&src[j * 8 + 4];
        union { unsigned u[4]; bf8 v; } o;
        o.u[0] = pack2(x0[0], x0[1]); o.u[1] = pack2(x0[2], x0[3]);
        o.u[2] = pack2(x1[0], x1[1]); o.u[3] = pack2(x1[2], x1[3]);
        *(bf8*)&dst[j * 8] = o.v;
    }
    if (tid < 128) lsb[(size_t)(b * SS + qg * 128 + tid) * 4 + h] = lsh[tid];
}

// ---------------------------------------------------------------------------
// Output projection via MFMA; merges the four KV-quarter partials in staging.
// ---------------------------------------------------------------------------
__global__ __launch_bounds__(256)
void out_proj_kernel(const __hip_bfloat16* __restrict__ po0,
                     const __hip_bfloat16* __restrict__ po1,
                     const __hip_bfloat16* __restrict__ po2,
                     const __hip_bfloat16* __restrict__ po3,
                     const float* __restrict__ ls0, const float* __restrict__ ls1,
                     const float* __restrict__ ls2, const float* __restrict__ ls3,
                     const __hip_bfloat16* __restrict__ wpk,
                     const float* __restrict__ bo, float* __restrict__ out)
{
    const int bid = blockIdx.x;
    const int stile = bid >> 1, grp = bid & 1;
    const int tid = threadIdx.x;
    const int w = tid >> 6, lane = tid & 63, hi = lane >> 5, l5 = lane & 31;

    __shared__ __hip_bfloat16 xs[32][256];
    {
        const int r0 = tid >> 5, c = tid & 31;
        #pragma unroll
        for (int it = 0; it < 4; ++it) {
            const int row = r0 + it * 8;
            const size_t srow = (size_t)stile * 32 + row;
            const int head = c >> 3;
            const float inv = 1.0f / (ls0[srow * 4 + head] + ls1[srow * 4 + head]
                                    + ls2[srow * 4 + head] + ls3[srow * 4 + head]);
            union { bf8 v; unsigned u[4]; } a0, a1, a2, a3;
            a0.v = *(const bf8*)&po0[srow * 256 + c * 8];
            a1.v = *(const bf8*)&po1[srow * 256 + c * 8];
            a2.v = *(const bf8*)&po2[srow * 256 + c * 8];
            a3.v = *(const bf8*)&po3[srow * 256 + c * 8];
            union { unsigned u[4]; bf8 v; } o;
            #pragma unroll
            for (int i = 0; i < 4; ++i) {
                const float lo = __uint_as_float(a0.u[i] << 16)
                               + __uint_as_float(a1.u[i] << 16)
                               + __uint_as_float(a2.u[i] << 16)
                               + __uint_as_float(a3.u[i] << 16);
                const float hv = __uint_as_float(a0.u[i] & 0xffff0000u)
                               + __uint_as_float(a1.u[i] & 0xffff0000u)
                               + __uint_as_float(a2.u[i] & 0xffff0000u)
                               + __uint_as_float(a3.u[i] & 0xffff0000u);
                o.u[i] = pack2(lo * inv, hv * inv);
            }
            *(bf8*)&xs[row][((c ^ row) & 31) * 8] = o.v;
        }
    }
    __syncthreads();

    const int nt = grp * 4 + w;           // 0..7
    const __hip_bfloat16* wb = wpk + (size_t)((3 * 8 + nt) * 16) * 512 + (size_t)lane * 8;
    bf8 wf[16];
    #pragma unroll
    for (int ks = 0; ks < 16; ++ks) wf[ks] = *(const bf8*)&wb[ks * 512];

    f16v acc;
    #pragma unroll
    for (int r = 0; r < 16; ++r) acc[r] = 0.0f;
    #pragma unroll
    for (int ks = 0; ks < 16; ++ks) {
        const bf8 xf = *(const bf8*)&xs[l5][(((ks * 2 + hi) ^ l5) & 31) * 8];
        acc = __builtin_amdgcn_mfma_f32_32x32x16_bf16(xf, wf[ks], acc, 0, 0, 0);
    }

    const float bn = bo[nt * 32 + l5];
    #pragma unroll
    for (int r = 0; r < 16; ++r) {
        const int sloc = (r & 3) + 8 * (r >> 2) + 4 * hi;
        out[(size_t)(stile * 32 + sloc) * HID + nt * 32 + l5] = acc[r] + bn;
    }
}

extern "C" void kernel_launch(void* const* d_in, const int* in_sizes, int n_in,
                              void* d_out, int out_size, void* d_ws, size_t ws_size,
                              hipStream_t stream)
{
    (void)in_sizes; (void)n_in; (void)out_size; (void)ws_size;
    const float* x        = (const float*)d_in[0];
    const int*   codons   = (const int*)d_in[1];
    const float* syn_bias = (const float*)d_in[2];
    const float* wq = (const float*)d_in[3];
    const float* bq = (const float*)d_in[4];
    const float* wk = (const float*)d_in[5];
    const float* bk = (const float*)d_in[6];
    const float* wv = (const float*)d_in[7];
    const float* bv = (const float*)d_in[8];
    const float* wo = (const float*)d_in[9];
    const float* bo = (const float*)d_in[10];
    float* out = (float*)d_out;

    char* ws = (char*)d_ws;
    int*   gid   = (int*)(ws);                                  // 256 B
    float* betaP = (float*)(ws + 256);                          // 4 B
    __hip_bfloat16* wpk   = (__hip_bfloat16*)(ws + 4096);       // 512 KB
    __hip_bfloat16* qfrag = (__hip_bfloat16*)(ws + (size_t)1048576u);    // 6.29 MB
    __hip_bfloat16* kfrag = (__hip_bfloat16*)(ws + (size_t)7340032u);    // 6.29 MB
    __hip_bfloat16* vfrag = (__hip_bfloat16*)(ws + (size_t)13631488u);   // 4.19 MB
    __hip_bfloat16* po0   = (__hip_bfloat16*)(ws + (size_t)17825792u);   // 4.19 MB
    __hip_bfloat16* po1   = (__hip_bfloat16*)(ws + (size_t)22020096u);   // 4.19 MB
    __hip_bfloat16* po2   = (__hip_bfloat16*)(ws + (size_t)26214400u);   // 4.19 MB
    __hip_bfloat16* po3   = (__hip_bfloat16*)(ws + (size_t)30408704u);   // 4.19 MB
    float* ls0            = (float*)(ws + (size_t)34603008u);            // 128 KB
    float* ls1            = (float*)(ws + (size_t)34734080u);            // 128 KB
    float* ls2            = (float*)(ws + (size_t)34865152u);            // 128 KB
    float* ls3            = (float*)(ws + (size_t)34996224u);            // 128 KB

    pack_w_kernel<<<128, 256, 0, stream>>>(wq, wk, wv, wo, syn_bias, gid, betaP, wpk);
    qkv_mfma_kernel<<<768, 256, 0, stream>>>(x, wpk, bq, bk, bv, codons, gid, betaP,
                                             qfrag, kfrag, vfrag);
    attn_kernel<<<1024, 256, 0, stream>>>(qfrag, kfrag, vfrag,
                                          po0, po1, po2, po3, ls0, ls1, ls2, ls3);
    out_proj_kernel<<<512, 256, 0, stream>>>(po0, po1, po2, po3,
                                             ls0, ls1, ls2, ls3, wpk, bo, out);
}